// Round 12
// baseline (227.902 us; speedup 1.0000x reference)
//
#include <hip/hip_runtime.h>

#define NPB_SHIFT 8
#define NPB 256          // nodes per bucket
#define EPB 8192         // edges per partition block
#define MAXB 512         // padded bucket count (NB = ceil(100000/256) = 391)
#define BCAP 9216        // fixed bucket capacity: E/NB=8184, sigma~90 -> +11 sigma
#define BPB 36           // blocks per bucket in expand (BCAP/256)
#define SRC_BITS 17      // N=100000 < 2^17
#define SRC_MASK 0x1FFFFu

// ---------------- K0: bucket cursor init: bcur[b] = b*BCAP ----------------
__global__ void bcur_init_kernel(unsigned int* __restrict__ bcur, int NB) {
    int b = blockIdx.x * blockDim.x + threadIdx.x;
    if (b < NB) bcur[b] = (unsigned int)b * BCAP;
}

// ---------------- K3: LDS-staged partition, packed u32 records ----------------
__global__ __launch_bounds__(256) void partition_kernel(const int* __restrict__ src,
                                                        const int* __restrict__ dst,
                                                        unsigned int* __restrict__ bcur,
                                                        unsigned int* __restrict__ staged, int E, int NB) {
    __shared__ unsigned int hist[MAXB], sc[MAXB], lbase[MAXB], lcur[MAXB], gbase[MAXB];
    __shared__ unsigned int stage[EPB];
    __shared__ unsigned short sbuck[EPB];
    int start = blockIdx.x * EPB;
    int cnt = min(EPB, E - start);
    for (int j = threadIdx.x; j < MAXB; j += 256) hist[j] = 0u;
    __syncthreads();
    for (int k = threadIdx.x; k < cnt; k += 256)
        atomicAdd(&hist[((unsigned int)dst[start + k]) >> NPB_SHIFT], 1u);
    __syncthreads();
    {
        int i0 = threadIdx.x, i1 = threadIdx.x + 256;
        sc[i0] = hist[i0]; sc[i1] = hist[i1];
        __syncthreads();
        for (int o = 1; o < MAXB; o <<= 1) {
            unsigned int v0 = (i0 >= o) ? sc[i0 - o] : 0u;
            unsigned int v1 = (i1 >= o) ? sc[i1 - o] : 0u;
            __syncthreads();
            sc[i0] += v0; sc[i1] += v1;
            __syncthreads();
        }
    }
    for (int j = threadIdx.x; j < MAXB; j += 256) {
        unsigned int c = hist[j];
        unsigned int ex = sc[j] - c;
        lbase[j] = ex; lcur[j] = ex;
        gbase[j] = (j < NB && c) ? atomicAdd(&bcur[j], c) : 0u;
    }
    __syncthreads();
    for (int k = threadIdx.x; k < cnt; k += 256) {
        unsigned int d = (unsigned int)dst[start + k];
        unsigned int b = d >> NPB_SHIFT;
        unsigned int pos = atomicAdd(&lcur[b], 1u);
        stage[pos] = ((d & (NPB - 1)) << SRC_BITS) | (unsigned int)src[start + k];
        sbuck[pos] = (unsigned short)b;
    }
    __syncthreads();
    for (int t = threadIdx.x; t < cnt; t += 256) {
        unsigned int b = sbuck[t];
        staged[(size_t)gbase[b] + (t - lbase[b])] = stage[t];
    }
}

// ---------------- K4: per-bucket exact CSR + off/deg/dinv/ttx ----------------
__global__ __launch_bounds__(256) void build_csr_kernel(const unsigned int* __restrict__ staged,
                                                        const unsigned int* __restrict__ bcur,
                                                        const float* __restrict__ x,
                                                        unsigned int* __restrict__ csr,
                                                        unsigned int* __restrict__ off,
                                                        unsigned int* __restrict__ deg,
                                                        float* __restrict__ dinv,
                                                        float* __restrict__ ttx, int N) {
    __shared__ unsigned int cnt[NPB], loff[NPB], ncur[NPB];
    int b = blockIdx.x;
    unsigned int base = (unsigned int)b * BCAP;
    unsigned int m = bcur[b] - base;
    int node0 = b << NPB_SHIFT;
    cnt[threadIdx.x] = 0u;
    __syncthreads();
    for (unsigned int t = threadIdx.x; t < m; t += 256)
        atomicAdd(&cnt[staged[(size_t)base + t] >> SRC_BITS], 1u);
    __syncthreads();
    unsigned int v = cnt[threadIdx.x];
    loff[threadIdx.x] = v;
    __syncthreads();
    for (int o = 1; o < NPB; o <<= 1) {
        unsigned int a = (threadIdx.x >= (unsigned)o) ? loff[threadIdx.x - o] : 0u;
        __syncthreads();
        loff[threadIdx.x] += a;
        __syncthreads();
    }
    unsigned int ex = loff[threadIdx.x] - v;
    ncur[threadIdx.x] = ex;
    int node = node0 + threadIdx.x;
    if (node < N) {
        off[node] = base + ex;
        deg[node] = v;
        float di = 1.0f / sqrtf((float)(v + 1u));  // +1 self loop
        dinv[node] = di;
        ttx[node] = di * x[node];
    }
    __syncthreads();
    for (unsigned int t = threadIdx.x; t < m; t += 256) {
        unsigned int rec = staged[(size_t)base + t];
        unsigned int p = atomicAdd(&ncur[rec >> SRC_BITS], 1u);
        csr[(size_t)base + p] = rec & SRC_MASK;
    }
}

// ---------------- LUT build: one block PER SEGMENT (65 blocks) ----------------
__global__ __launch_bounds__(256) void lut_kernel(const float* __restrict__ W1, const float* __restrict__ b1,
                                                  const float* __restrict__ W2,
                                                  float* __restrict__ Alut, float* __restrict__ Blut,
                                                  float* __restrict__ tvals) {
    __shared__ float w1[64], bb[64], tv[64];
    __shared__ int rnk[64];
    __shared__ float sW2[64 * 32];
    __shared__ double red[2][256];
    int tid = threadIdx.x;
    if (tid < 64) {
        float w = W1[tid], b = b1[tid];
        w1[tid] = w; bb[tid] = b;
        tv[tid] = (w != 0.f) ? (-b / w) : __uint_as_float(0x7F800000u);  // +inf for degenerate
    }
    for (int t = tid; t < 64 * 32; t += 256) sW2[t] = W2[t];
    __syncthreads();
    if (tid < 64) {
        int r = 0;
        float tj = tv[tid];
        for (int k = 0; k < 64; ++k)
            if (w1[k] != 0.f && (tv[k] < tj || (tv[k] == tj && k < tid))) ++r;
        rnk[tid] = r;
        if (blockIdx.x == 0) tvals[tid] = tv[tid];
    }
    __syncthreads();
    int s = blockIdx.x;                 // segment 0..64
    int c = tid & 31, slice = tid >> 5; // 8 j-slices x 32 channels
    double da = 0.0, db = 0.0;
#pragma unroll
    for (int u = 0; u < 8; ++u) {
        int j = slice * 8 + u;
        float w = w1[j];
        bool act = (w > 0.f) ? (rnk[j] < s) : ((w < 0.f) ? (rnk[j] >= s) : (bb[j] > 0.f));
        if (act) {
            double w2 = (double)sW2[j * 32 + c];
            da += (double)w * w2;
            db += (double)bb[j] * w2;
        }
    }
    red[0][tid] = da; red[1][tid] = db;
    __syncthreads();
    for (int o = 128; o >= 32; o >>= 1) {
        if (tid < o) { red[0][tid] += red[0][tid + o]; red[1][tid] += red[1][tid + o]; }
        __syncthreads();
    }
    if (tid < 32) {
        Alut[s * 32 + tid] = (float)red[0][tid];
        Blut[s * 32 + tid] = (float)red[1][tid];
    }
}

// ---------------- layer-1 gather + fused segment classification -> recs ----------------
__global__ __launch_bounds__(256) void gather1_kernel(const unsigned int* __restrict__ csr,
                                                      const unsigned int* __restrict__ off,
                                                      const unsigned int* __restrict__ deg,
                                                      const float* __restrict__ dinv,
                                                      const float* __restrict__ tt,
                                                      const float* __restrict__ tvals,
                                                      uint4* __restrict__ recs, int N) {
    __shared__ float st[64];
    for (int t = threadIdx.x; t < 64; t += 256) st[t] = tvals[t];
    __syncthreads();
    int tid = blockIdx.x * 256 + threadIdx.x;
    int i = tid >> 2, l = tid & 3;
    if (i >= N) return;
    unsigned int o = off[i], n = deg[i];
    float acc0 = 0.f, acc1 = 0.f;
    unsigned int k = l;
    for (; k + 4 < n; k += 8) { acc0 += tt[csr[o + k]]; acc1 += tt[csr[o + k + 4]]; }
    if (k < n) acc0 += tt[csr[o + k]];
    float acc = acc0 + acc1;
    acc += __shfl_xor(acc, 1, 4);
    acc += __shfl_xor(acc, 2, 4);
    float di = dinv[i];
    float a = di * (acc + tt[i]);        // agg1 (all 4 lanes hold it)
    unsigned int cv = 0;
#pragma unroll
    for (int j = 0; j < 16; ++j) cv += (st[l * 16 + j] < a) ? 1u : 0u;
    cv += __shfl_xor(cv, 1, 4);
    cv += __shfl_xor(cv, 2, 4);
    if (l == 0) recs[i] = make_uint4(__float_as_uint(a * di), __float_as_uint(di), cv, 0u);
}

// ---------------- edge expansion: erecs[slot] = recs[csr[slot]] ----------------
__global__ __launch_bounds__(256) void expand_kernel(const unsigned int* __restrict__ csr,
                                                     const unsigned int* __restrict__ bcur,
                                                     const uint4* __restrict__ recs,
                                                     uint4* __restrict__ erecs) {
    int b = blockIdx.x / BPB;
    unsigned int slot = (unsigned int)b * BCAP + (unsigned int)(blockIdx.x % BPB) * 256 + threadIdx.x;
    if (slot < bcur[b]) erecs[slot] = recs[csr[slot]];
}

// ---------------- layer-2 gather from SEQUENTIAL erecs + shuffle transform -> tt3 ----------------
#define G2_NODES 64
__global__ __launch_bounds__(256) void gather2t3_seq_kernel(const uint4* __restrict__ erecs,
                                                            const unsigned int* __restrict__ off,
                                                            const unsigned int* __restrict__ deg,
                                                            const float* __restrict__ dinv,
                                                            const uint4* __restrict__ recs,
                                                            const float* __restrict__ Alut, const float* __restrict__ Blut,
                                                            const float* __restrict__ b2, const float* __restrict__ W3,
                                                            float* __restrict__ tt3, int N) {
    __shared__ float4 sAB[65 * 16];
    __shared__ float sW3[32 * 16];
    __shared__ float sb2[32];
    for (int t = threadIdx.x; t < 65 * 16; t += 256) {
        int s = t >> 4, cc = t & 15;
        sAB[t] = make_float4(Alut[s * 32 + cc], Alut[s * 32 + cc + 16],
                             Blut[s * 32 + cc], Blut[s * 32 + cc + 16]);
    }
    for (int t = threadIdx.x; t < 32 * 16; t += 256) sW3[t] = W3[t];
    if (threadIdx.x < 32) sb2[threadIdx.x] = b2[threadIdx.x];
    __syncthreads();

    int g = threadIdx.x >> 4, c = threadIdx.x & 15;
    for (int iter = 0; iter < 4; ++iter) {
        int d = blockIdx.x * G2_NODES + iter * 16 + g;
        if (d >= N) continue;                 // uniform within the 16-lane group
        float dd = dinv[d];
        unsigned int o = off[d], n = deg[d];
        uint4 rs = recs[d];
        float ps = __uint_as_float(rs.x), qs = __uint_as_float(rs.y);
        float4 ABs = sAB[rs.z * 16 + c];
        float2 a0 = make_float2(fmaf(ABs.x, ps, ABs.z * qs), fmaf(ABs.y, ps, ABs.w * qs));
        float2 a1 = make_float2(0.f, 0.f), a2 = make_float2(0.f, 0.f), a3 = make_float2(0.f, 0.f);
        const uint4* ep = erecs + o;
        unsigned int k = 0;
        for (; k + 3 < n; k += 4) {
            uint4 r0 = ep[k], r1 = ep[k + 1], r2 = ep[k + 2], r3 = ep[k + 3];
            float4 A0 = sAB[r0.z * 16 + c], A1 = sAB[r1.z * 16 + c];
            float4 A2 = sAB[r2.z * 16 + c], A3 = sAB[r3.z * 16 + c];
            float p0 = __uint_as_float(r0.x), q0 = __uint_as_float(r0.y);
            float p1 = __uint_as_float(r1.x), q1 = __uint_as_float(r1.y);
            float p2 = __uint_as_float(r2.x), q2 = __uint_as_float(r2.y);
            float p3 = __uint_as_float(r3.x), q3 = __uint_as_float(r3.y);
            a0.x = fmaf(A0.x, p0, fmaf(A0.z, q0, a0.x));
            a0.y = fmaf(A0.y, p0, fmaf(A0.w, q0, a0.y));
            a1.x = fmaf(A1.x, p1, fmaf(A1.z, q1, a1.x));
            a1.y = fmaf(A1.y, p1, fmaf(A1.w, q1, a1.y));
            a2.x = fmaf(A2.x, p2, fmaf(A2.z, q2, a2.x));
            a2.y = fmaf(A2.y, p2, fmaf(A2.w, q2, a2.y));
            a3.x = fmaf(A3.x, p3, fmaf(A3.z, q3, a3.x));
            a3.y = fmaf(A3.y, p3, fmaf(A3.w, q3, a3.y));
        }
        for (; k < n; ++k) {
            uint4 r0 = ep[k];
            float4 A0 = sAB[r0.z * 16 + c];
            float p0 = __uint_as_float(r0.x), q0 = __uint_as_float(r0.y);
            a0.x = fmaf(A0.x, p0, fmaf(A0.z, q0, a0.x));
            a0.y = fmaf(A0.y, p0, fmaf(A0.w, q0, a0.y));
        }
        float hx = fmaxf(fmaf(dd, (a0.x + a1.x) + (a2.x + a3.x), sb2[c]), 0.f);
        float hy = fmaxf(fmaf(dd, (a0.y + a1.y) + (a2.y + a3.y), sb2[c + 16]), 0.f);

        float t3 = 0.f;
#pragma unroll
        for (int kk = 0; kk < 16; ++kk) {
            float hk = __shfl(hx, kk, 16);
            t3 = fmaf(hk, sW3[kk * 16 + c], t3);
        }
#pragma unroll
        for (int kk = 0; kk < 16; ++kk) {
            float hk = __shfl(hy, kk, 16);
            t3 = fmaf(hk, sW3[(kk + 16) * 16 + c], t3);
        }
        tt3[(size_t)d * 16 + c] = dd * t3;
    }
}

// ---------------- fallback layer-2 gather (r10 2-edge random-access path) ----------------
__global__ __launch_bounds__(256) void gather2t3_kernel(const unsigned int* __restrict__ csr,
                                                        const unsigned int* __restrict__ off,
                                                        const unsigned int* __restrict__ deg,
                                                        const float* __restrict__ dinv,
                                                        const uint4* __restrict__ recs,
                                                        const float* __restrict__ Alut, const float* __restrict__ Blut,
                                                        const float* __restrict__ b2, const float* __restrict__ W3,
                                                        float* __restrict__ tt3, int N) {
    __shared__ float4 sAB[65 * 16];
    __shared__ float sW3[32 * 16];
    __shared__ float sb2[32];
    for (int t = threadIdx.x; t < 65 * 16; t += 256) {
        int s = t >> 4, cc = t & 15;
        sAB[t] = make_float4(Alut[s * 32 + cc], Alut[s * 32 + cc + 16],
                             Blut[s * 32 + cc], Blut[s * 32 + cc + 16]);
    }
    for (int t = threadIdx.x; t < 32 * 16; t += 256) sW3[t] = W3[t];
    if (threadIdx.x < 32) sb2[threadIdx.x] = b2[threadIdx.x];
    __syncthreads();
    int g = threadIdx.x >> 4, c = threadIdx.x & 15;
    for (int iter = 0; iter < 4; ++iter) {
        int d = blockIdx.x * G2_NODES + iter * 16 + g;
        if (d >= N) continue;
        float dd = dinv[d];
        unsigned int o = off[d], n = deg[d];
        uint4 rs = recs[d];
        float ps = __uint_as_float(rs.x), qs = __uint_as_float(rs.y);
        float4 ABs = sAB[rs.z * 16 + c];
        float2 a0 = make_float2(fmaf(ABs.x, ps, ABs.z * qs), fmaf(ABs.y, ps, ABs.w * qs));
        float2 a1 = make_float2(0.f, 0.f);
        unsigned int k = 0;
        for (; k + 1 < n; k += 2) {
            unsigned int s0 = csr[o + k], s1 = csr[o + k + 1];
            uint4 r0 = recs[s0], r1 = recs[s1];
            float4 A0 = sAB[r0.z * 16 + c], A1 = sAB[r1.z * 16 + c];
            float p0 = __uint_as_float(r0.x), q0 = __uint_as_float(r0.y);
            float p1 = __uint_as_float(r1.x), q1 = __uint_as_float(r1.y);
            a0.x = fmaf(A0.x, p0, fmaf(A0.z, q0, a0.x));
            a0.y = fmaf(A0.y, p0, fmaf(A0.w, q0, a0.y));
            a1.x = fmaf(A1.x, p1, fmaf(A1.z, q1, a1.x));
            a1.y = fmaf(A1.y, p1, fmaf(A1.w, q1, a1.y));
        }
        if (k < n) {
            unsigned int s0 = csr[o + k];
            uint4 r0 = recs[s0];
            float4 A0 = sAB[r0.z * 16 + c];
            float p0 = __uint_as_float(r0.x), q0 = __uint_as_float(r0.y);
            a0.x = fmaf(A0.x, p0, fmaf(A0.z, q0, a0.x));
            a0.y = fmaf(A0.y, p0, fmaf(A0.w, q0, a0.y));
        }
        float hx = fmaxf(fmaf(dd, a0.x + a1.x, sb2[c]), 0.f);
        float hy = fmaxf(fmaf(dd, a0.y + a1.y, sb2[c + 16]), 0.f);
        float t3 = 0.f;
#pragma unroll
        for (int kk = 0; kk < 16; ++kk) {
            float hk = __shfl(hx, kk, 16);
            t3 = fmaf(hk, sW3[kk * 16 + c], t3);
        }
#pragma unroll
        for (int kk = 0; kk < 16; ++kk) {
            float hk = __shfl(hy, kk, 16);
            t3 = fmaf(hk, sW3[(kk + 16) * 16 + c], t3);
        }
        tt3[(size_t)d * 16 + c] = dd * t3;
    }
}

// ---------------- layer-3 gather (float4, 4 lanes/node, 4-edge unroll) -> tt4 ----------------
__global__ __launch_bounds__(256) void gather3t4_kernel(const unsigned int* __restrict__ csr,
                                                        const unsigned int* __restrict__ off,
                                                        const unsigned int* __restrict__ deg,
                                                        const float* __restrict__ dinv,
                                                        const float* __restrict__ tt3,
                                                        const float* __restrict__ b3, const float* __restrict__ W4,
                                                        float* __restrict__ tt4, int N) {
    int tid = blockIdx.x * 256 + threadIdx.x;
    int d = tid >> 2, l = tid & 3;
    if (d >= N) return;
    float dd = dinv[d];
    unsigned int o = off[d], n = deg[d];
    const float4* t34 = reinterpret_cast<const float4*>(tt3);
    float4 acc = t34[(size_t)d * 4 + l];   // self term
    float4 acc1 = make_float4(0.f, 0.f, 0.f, 0.f);
    unsigned int k = 0;
    for (; k + 3 < n; k += 4) {
        unsigned int s0 = csr[o + k], s1 = csr[o + k + 1], s2 = csr[o + k + 2], s3 = csr[o + k + 3];
        float4 v0 = t34[(size_t)s0 * 4 + l];
        float4 v1 = t34[(size_t)s1 * 4 + l];
        float4 v2 = t34[(size_t)s2 * 4 + l];
        float4 v3 = t34[(size_t)s3 * 4 + l];
        acc.x += v0.x + v2.x; acc.y += v0.y + v2.y; acc.z += v0.z + v2.z; acc.w += v0.w + v2.w;
        acc1.x += v1.x + v3.x; acc1.y += v1.y + v3.y; acc1.z += v1.z + v3.z; acc1.w += v1.w + v3.w;
    }
    for (; k < n; ++k) {
        float4 v0 = t34[(size_t)csr[o + k] * 4 + l];
        acc.x += v0.x; acc.y += v0.y; acc.z += v0.z; acc.w += v0.w;
    }
    acc.x += acc1.x; acc.y += acc1.y; acc.z += acc1.z; acc.w += acc1.w;
    float4 b3v = reinterpret_cast<const float4*>(b3)[l];
    float4 w4v = reinterpret_cast<const float4*>(W4)[l];
    float v = fmaxf(fmaf(dd, acc.x, b3v.x), 0.f) * w4v.x;
    v = fmaf(fmaxf(fmaf(dd, acc.y, b3v.y), 0.f), w4v.y, v);
    v = fmaf(fmaxf(fmaf(dd, acc.z, b3v.z), 0.f), w4v.z, v);
    v = fmaf(fmaxf(fmaf(dd, acc.w, b3v.w), 0.f), w4v.w, v);
    v += __shfl_xor(v, 1, 4);
    v += __shfl_xor(v, 2, 4);
    if (l == 0) tt4[d] = dd * v;
}

// ---------------- layer-4 scalar gather -> out ----------------
__global__ void gather4_kernel(const unsigned int* __restrict__ csr, const unsigned int* __restrict__ off,
                               const unsigned int* __restrict__ deg, const float* __restrict__ dinv,
                               const float* __restrict__ tt, const float* __restrict__ b4,
                               float* __restrict__ out, int N) {
    int tid = blockIdx.x * blockDim.x + threadIdx.x;
    int i = tid >> 2, l = tid & 3;
    if (i >= N) return;
    unsigned int o = off[i], n = deg[i];
    float acc0 = 0.f, acc1 = 0.f;
    unsigned int k = l;
    for (; k + 4 < n; k += 8) { acc0 += tt[csr[o + k]]; acc1 += tt[csr[o + k + 4]]; }
    if (k < n) acc0 += tt[csr[o + k]];
    float acc = acc0 + acc1;
    acc += __shfl_xor(acc, 1, 4);
    acc += __shfl_xor(acc, 2, 4);
    if (l == 0) out[i] = dinv[i] * (acc + tt[i]) + b4[0];
}

extern "C" void kernel_launch(void* const* d_in, const int* in_sizes, int n_in,
                              void* d_out, int out_size, void* d_ws, size_t ws_size,
                              hipStream_t stream) {
    const float* x  = (const float*)d_in[0];
    const int* eidx = (const int*)d_in[1];
    const float* W1 = (const float*)d_in[2];
    const float* b1 = (const float*)d_in[3];
    const float* W2 = (const float*)d_in[4];
    const float* b2 = (const float*)d_in[5];
    const float* W3 = (const float*)d_in[6];
    const float* b3 = (const float*)d_in[7];
    const float* W4 = (const float*)d_in[8];
    const float* b4 = (const float*)d_in[9];
    float* out = (float*)d_out;

    const int N = in_sizes[0];         // 100000
    const int E = in_sizes[1] / 2;     // 3200000
    const int* src = eidx;
    const int* dst = eidx + E;
    const int NB = (N + NPB - 1) >> NPB_SHIFT;   // 391 buckets

    char* ws = (char*)d_ws;
    char* ws0 = ws;
    unsigned int* bcur  = (unsigned int*)ws;  ws += MAXB * 4;
    float* tvals = (float*)ws;                ws += 64 * 4;
    float* Alut  = (float*)ws;                ws += 65 * 32 * 4;
    float* Blut  = (float*)ws;                ws += 65 * 32 * 4;
    unsigned int* off = (unsigned int*)ws;    ws += (size_t)N * 4;
    unsigned int* deg = (unsigned int*)ws;    ws += (size_t)N * 4;
    float* dinv = (float*)ws;                 ws += (size_t)N * 4;
    float* ttx  = (float*)ws;                 ws += (size_t)N * 4;
    float* tt4  = (float*)ws;                 ws += (size_t)N * 4;
    uint4* recs = (uint4*)ws;                 ws += (size_t)N * 16;
    unsigned int* csr = (unsigned int*)ws;    ws += (size_t)NB * BCAP * 4;   // padded CSR (14.4MB)
    unsigned int* staged = (unsigned int*)ws; ws += (size_t)NB * BCAP * 4;   // padded staged; tt3 aliases
    float* tt3 = (float*)staged;              // staged dead after build_csr
    uint4* erecs = (uint4*)ws;                // padded erecs (57.7MB) -- optional
    size_t need_erecs = (size_t)(ws - ws0) + (size_t)NB * BCAP * 16;
    const bool use_expand = (ws_size >= need_erecs);

    const int nPartBlocks = (E + EPB - 1) / EPB;

    bcur_init_kernel<<<(NB + 255) / 256, 256, 0, stream>>>(bcur, NB);
    partition_kernel<<<nPartBlocks, 256, 0, stream>>>(src, dst, bcur, staged, E, NB);
    build_csr_kernel<<<NB, 256, 0, stream>>>(staged, bcur, x, csr, off, deg, dinv, ttx, N);
    lut_kernel<<<65, 256, 0, stream>>>(W1, b1, W2, Alut, Blut, tvals);

    gather1_kernel<<<((size_t)N * 4 + 255) / 256, 256, 0, stream>>>(csr, off, deg, dinv, ttx, tvals, recs, N);
    if (use_expand) {
        expand_kernel<<<NB * BPB, 256, 0, stream>>>(csr, bcur, recs, erecs);
        gather2t3_seq_kernel<<<(N + G2_NODES - 1) / G2_NODES, 256, 0, stream>>>(erecs, off, deg, dinv, recs, Alut, Blut, b2, W3, tt3, N);
    } else {
        gather2t3_kernel<<<(N + G2_NODES - 1) / G2_NODES, 256, 0, stream>>>(csr, off, deg, dinv, recs, Alut, Blut, b2, W3, tt3, N);
    }
    gather3t4_kernel<<<((size_t)N * 4 + 255) / 256, 256, 0, stream>>>(csr, off, deg, dinv, tt3, b3, W4, tt4, N);
    gather4_kernel<<<((size_t)N * 4 + 255) / 256, 256, 0, stream>>>(csr, off, deg, dinv, tt4, b4, out, N);
}

// Round 13
// 216.262 us; speedup vs baseline: 1.0538x; 1.0538x over previous
//
#include <hip/hip_runtime.h>

#define NPB_SHIFT 8
#define NPB 256          // nodes per bucket
#define EPB 6144         // edges per partition block (521 blocks -> >=2/CU)
#define MAXB 512         // padded bucket count (NB = ceil(100000/256) = 391)
#define BCAP 9216        // fixed bucket capacity: E/NB=8184, sigma~90 -> +11 sigma
#define SRC_BITS 17      // N=100000 < 2^17
#define SRC_MASK 0x1FFFFu

// ---------------- K0: bucket cursor init: bcur[b] = b*BCAP ----------------
__global__ void bcur_init_kernel(unsigned int* __restrict__ bcur, int NB) {
    int b = blockIdx.x * blockDim.x + threadIdx.x;
    if (b < NB) bcur[b] = (unsigned int)b * BCAP;
}

// ---------------- K3: LDS-staged partition, packed u32 records ----------------
__global__ __launch_bounds__(256) void partition_kernel(const int* __restrict__ src,
                                                        const int* __restrict__ dst,
                                                        unsigned int* __restrict__ bcur,
                                                        unsigned int* __restrict__ staged, int E, int NB) {
    __shared__ unsigned int hist[MAXB], sc[MAXB], lbase[MAXB], lcur[MAXB], gbase[MAXB];
    __shared__ unsigned int stage[EPB];
    __shared__ unsigned short sbuck[EPB];
    int start = blockIdx.x * EPB;
    int cnt = min(EPB, E - start);
    for (int j = threadIdx.x; j < MAXB; j += 256) hist[j] = 0u;
    __syncthreads();
    for (int k = threadIdx.x; k < cnt; k += 256)
        atomicAdd(&hist[((unsigned int)dst[start + k]) >> NPB_SHIFT], 1u);
    __syncthreads();
    {
        int i0 = threadIdx.x, i1 = threadIdx.x + 256;
        sc[i0] = hist[i0]; sc[i1] = hist[i1];
        __syncthreads();
        for (int o = 1; o < MAXB; o <<= 1) {
            unsigned int v0 = (i0 >= o) ? sc[i0 - o] : 0u;
            unsigned int v1 = (i1 >= o) ? sc[i1 - o] : 0u;
            __syncthreads();
            sc[i0] += v0; sc[i1] += v1;
            __syncthreads();
        }
    }
    for (int j = threadIdx.x; j < MAXB; j += 256) {
        unsigned int c = hist[j];
        unsigned int ex = sc[j] - c;
        lbase[j] = ex; lcur[j] = ex;
        gbase[j] = (j < NB && c) ? atomicAdd(&bcur[j], c) : 0u;
    }
    __syncthreads();
    for (int k = threadIdx.x; k < cnt; k += 256) {
        unsigned int d = (unsigned int)dst[start + k];
        unsigned int b = d >> NPB_SHIFT;
        unsigned int pos = atomicAdd(&lcur[b], 1u);
        stage[pos] = ((d & (NPB - 1)) << SRC_BITS) | (unsigned int)src[start + k];
        sbuck[pos] = (unsigned short)b;
    }
    __syncthreads();
    for (int t = threadIdx.x; t < cnt; t += 256) {
        unsigned int b = sbuck[t];
        staged[(size_t)gbase[b] + (t - lbase[b])] = stage[t];
    }
}

// ---------------- K4: per-bucket exact CSR + off/deg/dinv/ttx ----------------
__global__ __launch_bounds__(256) void build_csr_kernel(const unsigned int* __restrict__ staged,
                                                        const unsigned int* __restrict__ bcur,
                                                        const float* __restrict__ x,
                                                        unsigned int* __restrict__ csr,
                                                        unsigned int* __restrict__ off,
                                                        unsigned int* __restrict__ deg,
                                                        float* __restrict__ dinv,
                                                        float* __restrict__ ttx, int N) {
    __shared__ unsigned int cnt[NPB], loff[NPB], ncur[NPB];
    int b = blockIdx.x;
    unsigned int base = (unsigned int)b * BCAP;
    unsigned int m = bcur[b] - base;
    int node0 = b << NPB_SHIFT;
    cnt[threadIdx.x] = 0u;
    __syncthreads();
    for (unsigned int t = threadIdx.x; t < m; t += 256)
        atomicAdd(&cnt[staged[(size_t)base + t] >> SRC_BITS], 1u);
    __syncthreads();
    unsigned int v = cnt[threadIdx.x];
    loff[threadIdx.x] = v;
    __syncthreads();
    for (int o = 1; o < NPB; o <<= 1) {
        unsigned int a = (threadIdx.x >= (unsigned)o) ? loff[threadIdx.x - o] : 0u;
        __syncthreads();
        loff[threadIdx.x] += a;
        __syncthreads();
    }
    unsigned int ex = loff[threadIdx.x] - v;
    ncur[threadIdx.x] = ex;
    int node = node0 + threadIdx.x;
    if (node < N) {
        off[node] = base + ex;
        deg[node] = v;
        float di = 1.0f / sqrtf((float)(v + 1u));  // +1 self loop
        dinv[node] = di;
        ttx[node] = di * x[node];
    }
    __syncthreads();
    for (unsigned int t = threadIdx.x; t < m; t += 256) {
        unsigned int rec = staged[(size_t)base + t];
        unsigned int p = atomicAdd(&ncur[rec >> SRC_BITS], 1u);
        csr[(size_t)base + p] = rec & SRC_MASK;
    }
}

// ---------------- LUT build: one block PER SEGMENT (65 blocks) ----------------
__global__ __launch_bounds__(256) void lut_kernel(const float* __restrict__ W1, const float* __restrict__ b1,
                                                  const float* __restrict__ W2,
                                                  float* __restrict__ Alut, float* __restrict__ Blut,
                                                  float* __restrict__ tvals) {
    __shared__ float w1[64], bb[64], tv[64];
    __shared__ int rnk[64];
    __shared__ float sW2[64 * 32];
    __shared__ double red[2][256];
    int tid = threadIdx.x;
    if (tid < 64) {
        float w = W1[tid], b = b1[tid];
        w1[tid] = w; bb[tid] = b;
        tv[tid] = (w != 0.f) ? (-b / w) : __uint_as_float(0x7F800000u);  // +inf for degenerate
    }
    for (int t = tid; t < 64 * 32; t += 256) sW2[t] = W2[t];
    __syncthreads();
    if (tid < 64) {
        int r = 0;
        float tj = tv[tid];
        for (int k = 0; k < 64; ++k)
            if (w1[k] != 0.f && (tv[k] < tj || (tv[k] == tj && k < tid))) ++r;
        rnk[tid] = r;
        if (blockIdx.x == 0) tvals[tid] = tv[tid];
    }
    __syncthreads();
    int s = blockIdx.x;                 // segment 0..64
    int c = tid & 31, slice = tid >> 5; // 8 j-slices x 32 channels
    double da = 0.0, db = 0.0;
#pragma unroll
    for (int u = 0; u < 8; ++u) {
        int j = slice * 8 + u;
        float w = w1[j];
        bool act = (w > 0.f) ? (rnk[j] < s) : ((w < 0.f) ? (rnk[j] >= s) : (bb[j] > 0.f));
        if (act) {
            double w2 = (double)sW2[j * 32 + c];
            da += (double)w * w2;
            db += (double)bb[j] * w2;
        }
    }
    red[0][tid] = da; red[1][tid] = db;
    __syncthreads();
    for (int o = 128; o >= 32; o >>= 1) {
        if (tid < o) { red[0][tid] += red[0][tid + o]; red[1][tid] += red[1][tid + o]; }
        __syncthreads();
    }
    if (tid < 32) {
        Alut[s * 32 + tid] = (float)red[0][tid];
        Blut[s * 32 + tid] = (float)red[1][tid];
    }
}

// ---------------- layer-1 gather + fused segment classification -> recs ----------------
__global__ __launch_bounds__(256) void gather1_kernel(const unsigned int* __restrict__ csr,
                                                      const unsigned int* __restrict__ off,
                                                      const unsigned int* __restrict__ deg,
                                                      const float* __restrict__ dinv,
                                                      const float* __restrict__ tt,
                                                      const float* __restrict__ tvals,
                                                      uint4* __restrict__ recs, int N) {
    __shared__ float st[64];
    for (int t = threadIdx.x; t < 64; t += 256) st[t] = tvals[t];
    __syncthreads();
    int tid = blockIdx.x * 256 + threadIdx.x;
    int i = tid >> 2, l = tid & 3;
    if (i >= N) return;
    unsigned int o = off[i], n = deg[i];
    float acc0 = 0.f, acc1 = 0.f;
    unsigned int k = l;
    for (; k + 4 < n; k += 8) { acc0 += tt[csr[o + k]]; acc1 += tt[csr[o + k + 4]]; }
    if (k < n) acc0 += tt[csr[o + k]];
    float acc = acc0 + acc1;
    acc += __shfl_xor(acc, 1, 4);
    acc += __shfl_xor(acc, 2, 4);
    float di = dinv[i];
    float a = di * (acc + tt[i]);        // agg1 (all 4 lanes hold it)
    unsigned int cv = 0;
#pragma unroll
    for (int j = 0; j < 16; ++j) cv += (st[l * 16 + j] < a) ? 1u : 0u;
    cv += __shfl_xor(cv, 1, 4);
    cv += __shfl_xor(cv, 2, 4);
    if (l == 0) recs[i] = make_uint4(__float_as_uint(a * di), __float_as_uint(di), cv, 0u);
}

// ---------------- layer-2 LUT gather + in-register shuffle transform -> tt3 ----------------
// 16 lanes/node, lane owns channels (c, c+16); zero barriers after init;
// 1-deep software pipeline: next pair's recs loads issue before current pair's FMAs.
#define G2_NODES 64
__global__ __launch_bounds__(256) void gather2t3_kernel(const unsigned int* __restrict__ csr,
                                                        const unsigned int* __restrict__ off,
                                                        const unsigned int* __restrict__ deg,
                                                        const float* __restrict__ dinv,
                                                        const uint4* __restrict__ recs,
                                                        const float* __restrict__ Alut, const float* __restrict__ Blut,
                                                        const float* __restrict__ b2, const float* __restrict__ W3,
                                                        float* __restrict__ tt3, int N) {
    __shared__ float4 sAB[65 * 16];
    __shared__ float sW3[32 * 16];
    __shared__ float sb2[32];
    for (int t = threadIdx.x; t < 65 * 16; t += 256) {
        int s = t >> 4, cc = t & 15;
        sAB[t] = make_float4(Alut[s * 32 + cc], Alut[s * 32 + cc + 16],
                             Blut[s * 32 + cc], Blut[s * 32 + cc + 16]);
    }
    for (int t = threadIdx.x; t < 32 * 16; t += 256) sW3[t] = W3[t];
    if (threadIdx.x < 32) sb2[threadIdx.x] = b2[threadIdx.x];
    __syncthreads();

    int g = threadIdx.x >> 4, c = threadIdx.x & 15;
    for (int iter = 0; iter < 4; ++iter) {
        int d = blockIdx.x * G2_NODES + iter * 16 + g;
        if (d >= N) continue;                 // uniform within the 16-lane group
        float dd = dinv[d];
        unsigned int o = off[d], n = deg[d];
        uint4 rs = recs[d];
        float ps = __uint_as_float(rs.x), qs = __uint_as_float(rs.y);
        float4 ABs = sAB[rs.z * 16 + c];
        float2 a0 = make_float2(fmaf(ABs.x, ps, ABs.z * qs), fmaf(ABs.y, ps, ABs.w * qs));
        float2 a1 = make_float2(0.f, 0.f);
        unsigned int k = 0;
        if (n >= 2) {
            uint4 r0 = recs[csr[o]], r1 = recs[csr[o + 1]];
            unsigned int kk = 2;
            for (; kk + 1 < n; kk += 2) {
                uint4 nr0 = recs[csr[o + kk]];        // issue next pair's loads
                uint4 nr1 = recs[csr[o + kk + 1]];
                float4 A0 = sAB[r0.z * 16 + c], A1 = sAB[r1.z * 16 + c];
                float p0 = __uint_as_float(r0.x), q0 = __uint_as_float(r0.y);
                float p1 = __uint_as_float(r1.x), q1 = __uint_as_float(r1.y);
                a0.x = fmaf(A0.x, p0, fmaf(A0.z, q0, a0.x));
                a0.y = fmaf(A0.y, p0, fmaf(A0.w, q0, a0.y));
                a1.x = fmaf(A1.x, p1, fmaf(A1.z, q1, a1.x));
                a1.y = fmaf(A1.y, p1, fmaf(A1.w, q1, a1.y));
                r0 = nr0; r1 = nr1;
            }
            {   // drain the last in-flight pair
                float4 A0 = sAB[r0.z * 16 + c], A1 = sAB[r1.z * 16 + c];
                float p0 = __uint_as_float(r0.x), q0 = __uint_as_float(r0.y);
                float p1 = __uint_as_float(r1.x), q1 = __uint_as_float(r1.y);
                a0.x = fmaf(A0.x, p0, fmaf(A0.z, q0, a0.x));
                a0.y = fmaf(A0.y, p0, fmaf(A0.w, q0, a0.y));
                a1.x = fmaf(A1.x, p1, fmaf(A1.z, q1, a1.x));
                a1.y = fmaf(A1.y, p1, fmaf(A1.w, q1, a1.y));
            }
            k = kk;
        }
        if (k < n) {                          // odd tail
            uint4 r0 = recs[csr[o + k]];
            float4 A0 = sAB[r0.z * 16 + c];
            float p0 = __uint_as_float(r0.x), q0 = __uint_as_float(r0.y);
            a0.x = fmaf(A0.x, p0, fmaf(A0.z, q0, a0.x));
            a0.y = fmaf(A0.y, p0, fmaf(A0.w, q0, a0.y));
        }
        float hx = fmaxf(fmaf(dd, a0.x + a1.x, sb2[c]), 0.f);        // h2[c]
        float hy = fmaxf(fmaf(dd, a0.y + a1.y, sb2[c + 16]), 0.f);   // h2[c+16]

        // in-register W3 transform: t3[c] = sum_k h2[k] * W3[k][c]
        float t3 = 0.f;
#pragma unroll
        for (int kk = 0; kk < 16; ++kk) {
            float hk = __shfl(hx, kk, 16);
            t3 = fmaf(hk, sW3[kk * 16 + c], t3);
        }
#pragma unroll
        for (int kk = 0; kk < 16; ++kk) {
            float hk = __shfl(hy, kk, 16);
            t3 = fmaf(hk, sW3[(kk + 16) * 16 + c], t3);
        }
        tt3[(size_t)d * 16 + c] = dd * t3;
    }
}

// ---------------- layer-3 gather (float4, 4 lanes/node, 4-edge unroll) -> tt4 ----------------
__global__ __launch_bounds__(256) void gather3t4_kernel(const unsigned int* __restrict__ csr,
                                                        const unsigned int* __restrict__ off,
                                                        const unsigned int* __restrict__ deg,
                                                        const float* __restrict__ dinv,
                                                        const float* __restrict__ tt3,
                                                        const float* __restrict__ b3, const float* __restrict__ W4,
                                                        float* __restrict__ tt4, int N) {
    int tid = blockIdx.x * 256 + threadIdx.x;
    int d = tid >> 2, l = tid & 3;
    if (d >= N) return;
    float dd = dinv[d];
    unsigned int o = off[d], n = deg[d];
    const float4* t34 = reinterpret_cast<const float4*>(tt3);
    float4 acc = t34[(size_t)d * 4 + l];   // self term
    float4 acc1 = make_float4(0.f, 0.f, 0.f, 0.f);
    unsigned int k = 0;
    for (; k + 3 < n; k += 4) {
        unsigned int s0 = csr[o + k], s1 = csr[o + k + 1], s2 = csr[o + k + 2], s3 = csr[o + k + 3];
        float4 v0 = t34[(size_t)s0 * 4 + l];
        float4 v1 = t34[(size_t)s1 * 4 + l];
        float4 v2 = t34[(size_t)s2 * 4 + l];
        float4 v3 = t34[(size_t)s3 * 4 + l];
        acc.x += v0.x + v2.x; acc.y += v0.y + v2.y; acc.z += v0.z + v2.z; acc.w += v0.w + v2.w;
        acc1.x += v1.x + v3.x; acc1.y += v1.y + v3.y; acc1.z += v1.z + v3.z; acc1.w += v1.w + v3.w;
    }
    for (; k < n; ++k) {
        float4 v0 = t34[(size_t)csr[o + k] * 4 + l];
        acc.x += v0.x; acc.y += v0.y; acc.z += v0.z; acc.w += v0.w;
    }
    acc.x += acc1.x; acc.y += acc1.y; acc.z += acc1.z; acc.w += acc1.w;
    float4 b3v = reinterpret_cast<const float4*>(b3)[l];
    float4 w4v = reinterpret_cast<const float4*>(W4)[l];
    float v = fmaxf(fmaf(dd, acc.x, b3v.x), 0.f) * w4v.x;
    v = fmaf(fmaxf(fmaf(dd, acc.y, b3v.y), 0.f), w4v.y, v);
    v = fmaf(fmaxf(fmaf(dd, acc.z, b3v.z), 0.f), w4v.z, v);
    v = fmaf(fmaxf(fmaf(dd, acc.w, b3v.w), 0.f), w4v.w, v);
    v += __shfl_xor(v, 1, 4);
    v += __shfl_xor(v, 2, 4);
    if (l == 0) tt4[d] = dd * v;
}

// ---------------- layer-4 scalar gather -> out ----------------
__global__ void gather4_kernel(const unsigned int* __restrict__ csr, const unsigned int* __restrict__ off,
                               const unsigned int* __restrict__ deg, const float* __restrict__ dinv,
                               const float* __restrict__ tt, const float* __restrict__ b4,
                               float* __restrict__ out, int N) {
    int tid = blockIdx.x * blockDim.x + threadIdx.x;
    int i = tid >> 2, l = tid & 3;
    if (i >= N) return;
    unsigned int o = off[i], n = deg[i];
    float acc0 = 0.f, acc1 = 0.f;
    unsigned int k = l;
    for (; k + 4 < n; k += 8) { acc0 += tt[csr[o + k]]; acc1 += tt[csr[o + k + 4]]; }
    if (k < n) acc0 += tt[csr[o + k]];
    float acc = acc0 + acc1;
    acc += __shfl_xor(acc, 1, 4);
    acc += __shfl_xor(acc, 2, 4);
    if (l == 0) out[i] = dinv[i] * (acc + tt[i]) + b4[0];
}

extern "C" void kernel_launch(void* const* d_in, const int* in_sizes, int n_in,
                              void* d_out, int out_size, void* d_ws, size_t ws_size,
                              hipStream_t stream) {
    const float* x  = (const float*)d_in[0];
    const int* eidx = (const int*)d_in[1];
    const float* W1 = (const float*)d_in[2];
    const float* b1 = (const float*)d_in[3];
    const float* W2 = (const float*)d_in[4];
    const float* b2 = (const float*)d_in[5];
    const float* W3 = (const float*)d_in[6];
    const float* b3 = (const float*)d_in[7];
    const float* W4 = (const float*)d_in[8];
    const float* b4 = (const float*)d_in[9];
    float* out = (float*)d_out;

    const int N = in_sizes[0];         // 100000
    const int E = in_sizes[1] / 2;     // 3200000
    const int* src = eidx;
    const int* dst = eidx + E;
    const int NB = (N + NPB - 1) >> NPB_SHIFT;   // 391 buckets

    char* ws = (char*)d_ws;
    unsigned int* bcur  = (unsigned int*)ws;  ws += MAXB * 4;
    float* tvals = (float*)ws;                ws += 64 * 4;
    float* Alut  = (float*)ws;                ws += 65 * 32 * 4;
    float* Blut  = (float*)ws;                ws += 65 * 32 * 4;
    unsigned int* off = (unsigned int*)ws;    ws += (size_t)N * 4;
    unsigned int* deg = (unsigned int*)ws;    ws += (size_t)N * 4;
    float* dinv = (float*)ws;                 ws += (size_t)N * 4;
    float* ttx  = (float*)ws;                 ws += (size_t)N * 4;
    float* tt4  = (float*)ws;                 ws += (size_t)N * 4;
    uint4* recs = (uint4*)ws;                 ws += (size_t)N * 16;
    unsigned int* csr = (unsigned int*)ws;    ws += (size_t)NB * BCAP * 4;   // padded CSR (14.4MB)
    unsigned int* staged = (unsigned int*)ws; // padded staged; tt3 (6.4MB) aliases it
    float* tt3 = (float*)staged;              // staged dead after build_csr

    const int nPartBlocks = (E + EPB - 1) / EPB;   // 521

    bcur_init_kernel<<<(NB + 255) / 256, 256, 0, stream>>>(bcur, NB);
    partition_kernel<<<nPartBlocks, 256, 0, stream>>>(src, dst, bcur, staged, E, NB);
    build_csr_kernel<<<NB, 256, 0, stream>>>(staged, bcur, x, csr, off, deg, dinv, ttx, N);
    lut_kernel<<<65, 256, 0, stream>>>(W1, b1, W2, Alut, Blut, tvals);

    gather1_kernel<<<((size_t)N * 4 + 255) / 256, 256, 0, stream>>>(csr, off, deg, dinv, ttx, tvals, recs, N);
    gather2t3_kernel<<<(N + G2_NODES - 1) / G2_NODES, 256, 0, stream>>>(csr, off, deg, dinv, recs, Alut, Blut, b2, W3, tt3, N);
    gather3t4_kernel<<<((size_t)N * 4 + 255) / 256, 256, 0, stream>>>(csr, off, deg, dinv, tt3, b3, W4, tt4, N);
    gather4_kernel<<<((size_t)N * 4 + 255) / 256, 256, 0, stream>>>(csr, off, deg, dinv, tt4, b4, out, N);
}

// Round 14
// 209.242 us; speedup vs baseline: 1.0892x; 1.0335x over previous
//
#include <hip/hip_runtime.h>

#define NPB_SHIFT 8
#define NPB 256          // nodes per bucket
#define EPB 6144         // edges per partition block (521 blocks -> >=2/CU)
#define MAXB 512         // padded bucket count (NB = ceil(100000/256) = 391)
#define BCAP 9216        // fixed bucket capacity: E/NB=8184, sigma~90 -> +11 sigma
#define SRC_BITS 17      // N=100000 < 2^17
#define SRC_MASK 0x1FFFFu

// ---------------- K0: bucket cursor init: bcur[b] = b*BCAP ----------------
__global__ void bcur_init_kernel(unsigned int* __restrict__ bcur, int NB) {
    int b = blockIdx.x * blockDim.x + threadIdx.x;
    if (b < NB) bcur[b] = (unsigned int)b * BCAP;
}

// ---------------- K3: LDS-staged partition, packed u32 records ----------------
__global__ __launch_bounds__(256) void partition_kernel(const int* __restrict__ src,
                                                        const int* __restrict__ dst,
                                                        unsigned int* __restrict__ bcur,
                                                        unsigned int* __restrict__ staged, int E, int NB) {
    __shared__ unsigned int hist[MAXB], sc[MAXB], lbase[MAXB], lcur[MAXB], gbase[MAXB];
    __shared__ unsigned int stage[EPB];
    __shared__ unsigned short sbuck[EPB];
    int start = blockIdx.x * EPB;
    int cnt = min(EPB, E - start);
    for (int j = threadIdx.x; j < MAXB; j += 256) hist[j] = 0u;
    __syncthreads();
    for (int k = threadIdx.x; k < cnt; k += 256)
        atomicAdd(&hist[((unsigned int)dst[start + k]) >> NPB_SHIFT], 1u);
    __syncthreads();
    {
        int i0 = threadIdx.x, i1 = threadIdx.x + 256;
        sc[i0] = hist[i0]; sc[i1] = hist[i1];
        __syncthreads();
        for (int o = 1; o < MAXB; o <<= 1) {
            unsigned int v0 = (i0 >= o) ? sc[i0 - o] : 0u;
            unsigned int v1 = (i1 >= o) ? sc[i1 - o] : 0u;
            __syncthreads();
            sc[i0] += v0; sc[i1] += v1;
            __syncthreads();
        }
    }
    for (int j = threadIdx.x; j < MAXB; j += 256) {
        unsigned int c = hist[j];
        unsigned int ex = sc[j] - c;
        lbase[j] = ex; lcur[j] = ex;
        gbase[j] = (j < NB && c) ? atomicAdd(&bcur[j], c) : 0u;
    }
    __syncthreads();
    for (int k = threadIdx.x; k < cnt; k += 256) {
        unsigned int d = (unsigned int)dst[start + k];
        unsigned int b = d >> NPB_SHIFT;
        unsigned int pos = atomicAdd(&lcur[b], 1u);
        stage[pos] = ((d & (NPB - 1)) << SRC_BITS) | (unsigned int)src[start + k];
        sbuck[pos] = (unsigned short)b;
    }
    __syncthreads();
    for (int t = threadIdx.x; t < cnt; t += 256) {
        unsigned int b = sbuck[t];
        staged[(size_t)gbase[b] + (t - lbase[b])] = stage[t];
    }
}

// ---------------- K4: per-bucket exact CSR + off/deg/dinv/ttx ----------------
__global__ __launch_bounds__(256) void build_csr_kernel(const unsigned int* __restrict__ staged,
                                                        const unsigned int* __restrict__ bcur,
                                                        const float* __restrict__ x,
                                                        unsigned int* __restrict__ csr,
                                                        unsigned int* __restrict__ off,
                                                        unsigned int* __restrict__ deg,
                                                        float* __restrict__ dinv,
                                                        float* __restrict__ ttx, int N) {
    __shared__ unsigned int cnt[NPB], loff[NPB], ncur[NPB];
    int b = blockIdx.x;
    unsigned int base = (unsigned int)b * BCAP;
    unsigned int m = bcur[b] - base;
    int node0 = b << NPB_SHIFT;
    cnt[threadIdx.x] = 0u;
    __syncthreads();
    for (unsigned int t = threadIdx.x; t < m; t += 256)
        atomicAdd(&cnt[staged[(size_t)base + t] >> SRC_BITS], 1u);
    __syncthreads();
    unsigned int v = cnt[threadIdx.x];
    loff[threadIdx.x] = v;
    __syncthreads();
    for (int o = 1; o < NPB; o <<= 1) {
        unsigned int a = (threadIdx.x >= (unsigned)o) ? loff[threadIdx.x - o] : 0u;
        __syncthreads();
        loff[threadIdx.x] += a;
        __syncthreads();
    }
    unsigned int ex = loff[threadIdx.x] - v;
    ncur[threadIdx.x] = ex;
    int node = node0 + threadIdx.x;
    if (node < N) {
        off[node] = base + ex;
        deg[node] = v;
        float di = 1.0f / sqrtf((float)(v + 1u));  // +1 self loop
        dinv[node] = di;
        ttx[node] = di * x[node];
    }
    __syncthreads();
    for (unsigned int t = threadIdx.x; t < m; t += 256) {
        unsigned int rec = staged[(size_t)base + t];
        unsigned int p = atomicAdd(&ncur[rec >> SRC_BITS], 1u);
        csr[(size_t)base + p] = rec & SRC_MASK;
    }
}

// ---------------- LUT build: one block PER SEGMENT (65 blocks) ----------------
__global__ __launch_bounds__(256) void lut_kernel(const float* __restrict__ W1, const float* __restrict__ b1,
                                                  const float* __restrict__ W2,
                                                  float* __restrict__ Alut, float* __restrict__ Blut,
                                                  float* __restrict__ tvals) {
    __shared__ float w1[64], bb[64], tv[64];
    __shared__ int rnk[64];
    __shared__ float sW2[64 * 32];
    __shared__ double red[2][256];
    int tid = threadIdx.x;
    if (tid < 64) {
        float w = W1[tid], b = b1[tid];
        w1[tid] = w; bb[tid] = b;
        tv[tid] = (w != 0.f) ? (-b / w) : __uint_as_float(0x7F800000u);  // +inf for degenerate
    }
    for (int t = tid; t < 64 * 32; t += 256) sW2[t] = W2[t];
    __syncthreads();
    if (tid < 64) {
        int r = 0;
        float tj = tv[tid];
        for (int k = 0; k < 64; ++k)
            if (w1[k] != 0.f && (tv[k] < tj || (tv[k] == tj && k < tid))) ++r;
        rnk[tid] = r;
        if (blockIdx.x == 0) tvals[tid] = tv[tid];
    }
    __syncthreads();
    int s = blockIdx.x;                 // segment 0..64
    int c = tid & 31, slice = tid >> 5; // 8 j-slices x 32 channels
    double da = 0.0, db = 0.0;
#pragma unroll
    for (int u = 0; u < 8; ++u) {
        int j = slice * 8 + u;
        float w = w1[j];
        bool act = (w > 0.f) ? (rnk[j] < s) : ((w < 0.f) ? (rnk[j] >= s) : (bb[j] > 0.f));
        if (act) {
            double w2 = (double)sW2[j * 32 + c];
            da += (double)w * w2;
            db += (double)bb[j] * w2;
        }
    }
    red[0][tid] = da; red[1][tid] = db;
    __syncthreads();
    for (int o = 128; o >= 32; o >>= 1) {
        if (tid < o) { red[0][tid] += red[0][tid + o]; red[1][tid] += red[1][tid + o]; }
        __syncthreads();
    }
    if (tid < 32) {
        Alut[s * 32 + tid] = (float)red[0][tid];
        Blut[s * 32 + tid] = (float)red[1][tid];
    }
}

// ---------------- layer-1 gather + fused segment classification -> recs ----------------
__global__ __launch_bounds__(256) void gather1_kernel(const unsigned int* __restrict__ csr,
                                                      const unsigned int* __restrict__ off,
                                                      const unsigned int* __restrict__ deg,
                                                      const float* __restrict__ dinv,
                                                      const float* __restrict__ tt,
                                                      const float* __restrict__ tvals,
                                                      uint4* __restrict__ recs, int N) {
    __shared__ float st[64];
    for (int t = threadIdx.x; t < 64; t += 256) st[t] = tvals[t];
    __syncthreads();
    int tid = blockIdx.x * 256 + threadIdx.x;
    int i = tid >> 2, l = tid & 3;
    if (i >= N) return;
    unsigned int o = off[i], n = deg[i];
    float acc0 = 0.f, acc1 = 0.f;
    unsigned int k = l;
    for (; k + 4 < n; k += 8) { acc0 += tt[csr[o + k]]; acc1 += tt[csr[o + k + 4]]; }
    if (k < n) acc0 += tt[csr[o + k]];
    float acc = acc0 + acc1;
    acc += __shfl_xor(acc, 1, 4);
    acc += __shfl_xor(acc, 2, 4);
    float di = dinv[i];
    float a = di * (acc + tt[i]);        // agg1 (all 4 lanes hold it)
    unsigned int cv = 0;
#pragma unroll
    for (int j = 0; j < 16; ++j) cv += (st[l * 16 + j] < a) ? 1u : 0u;
    cv += __shfl_xor(cv, 1, 4);
    cv += __shfl_xor(cv, 2, 4);
    if (l == 0) recs[i] = make_uint4(__float_as_uint(a * di), __float_as_uint(di), cv, 0u);
}

// ---------------- layer-2 LUT gather + in-register shuffle transform -> tt3 ----------------
// 16 lanes/node; 2-STAGE rotating pipeline: csr(pair j+2) and recs(pair j+1) issue
// while FMAing pair j -> ~4 loads in flight per group (dependency distance = 1 iter).
#define G2_NODES 64
#define FMA_REC(R, AX, AY)                                                   \
    {                                                                        \
        float4 A_ = sAB[(R).z * 16 + c];                                     \
        float p_ = __uint_as_float((R).x), q_ = __uint_as_float((R).y);      \
        (AX).x = fmaf(A_.x, p_, fmaf(A_.z, q_, (AX).x));                     \
        (AX).y = fmaf(A_.y, p_, fmaf(A_.w, q_, (AX).y));                     \
        (void)(AY);                                                          \
    }
__global__ __launch_bounds__(256) void gather2t3_kernel(const unsigned int* __restrict__ csr,
                                                        const unsigned int* __restrict__ off,
                                                        const unsigned int* __restrict__ deg,
                                                        const float* __restrict__ dinv,
                                                        const uint4* __restrict__ recs,
                                                        const float* __restrict__ Alut, const float* __restrict__ Blut,
                                                        const float* __restrict__ b2, const float* __restrict__ W3,
                                                        float* __restrict__ tt3, int N) {
    __shared__ float4 sAB[65 * 16];
    __shared__ float sW3[32 * 16];
    __shared__ float sb2[32];
    for (int t = threadIdx.x; t < 65 * 16; t += 256) {
        int s = t >> 4, cc = t & 15;
        sAB[t] = make_float4(Alut[s * 32 + cc], Alut[s * 32 + cc + 16],
                             Blut[s * 32 + cc], Blut[s * 32 + cc + 16]);
    }
    for (int t = threadIdx.x; t < 32 * 16; t += 256) sW3[t] = W3[t];
    if (threadIdx.x < 32) sb2[threadIdx.x] = b2[threadIdx.x];
    __syncthreads();

    int g = threadIdx.x >> 4, c = threadIdx.x & 15;
    for (int iter = 0; iter < 4; ++iter) {
        int d = blockIdx.x * G2_NODES + iter * 16 + g;
        if (d >= N) continue;                 // uniform within the 16-lane group
        float dd = dinv[d];
        unsigned int o = off[d], n = deg[d];
        uint4 rs = recs[d];
        float ps = __uint_as_float(rs.x), qs = __uint_as_float(rs.y);
        float4 ABs = sAB[rs.z * 16 + c];
        float2 a0 = make_float2(fmaf(ABs.x, ps, ABs.z * qs), fmaf(ABs.y, ps, ABs.w * qs));
        float2 a1 = make_float2(0.f, 0.f);
        unsigned int P = n >> 1;
        if (P >= 2) {
            // prologue: csr pair0 + recs pair0, csr pair1
            unsigned int c0 = csr[o], c1 = csr[o + 1];
            unsigned int c2 = csr[o + 2], c3 = csr[o + 3];
            uint4 r0 = recs[c0], r1 = recs[c1];
            for (unsigned int j = 0; j + 2 < P; ++j) {
                unsigned int base = o + 2 * j;
                unsigned int nc0 = csr[base + 4], nc1 = csr[base + 5];  // csr pair j+2
                uint4 nr0 = recs[c2], nr1 = recs[c3];                   // recs pair j+1
                {   // FMA pair j
                    float4 A0 = sAB[r0.z * 16 + c], A1 = sAB[r1.z * 16 + c];
                    float p0 = __uint_as_float(r0.x), q0 = __uint_as_float(r0.y);
                    float p1 = __uint_as_float(r1.x), q1 = __uint_as_float(r1.y);
                    a0.x = fmaf(A0.x, p0, fmaf(A0.z, q0, a0.x));
                    a0.y = fmaf(A0.y, p0, fmaf(A0.w, q0, a0.y));
                    a1.x = fmaf(A1.x, p1, fmaf(A1.z, q1, a1.x));
                    a1.y = fmaf(A1.y, p1, fmaf(A1.w, q1, a1.y));
                }
                r0 = nr0; r1 = nr1; c2 = nc0; c3 = nc1;
            }
            // epilogue: FMA pair P-2 (in r), then load+FMA pair P-1 (csr already in c2,c3)
            uint4 m0 = recs[c2], m1 = recs[c3];
            {
                float4 A0 = sAB[r0.z * 16 + c], A1 = sAB[r1.z * 16 + c];
                float p0 = __uint_as_float(r0.x), q0 = __uint_as_float(r0.y);
                float p1 = __uint_as_float(r1.x), q1 = __uint_as_float(r1.y);
                a0.x = fmaf(A0.x, p0, fmaf(A0.z, q0, a0.x));
                a0.y = fmaf(A0.y, p0, fmaf(A0.w, q0, a0.y));
                a1.x = fmaf(A1.x, p1, fmaf(A1.z, q1, a1.x));
                a1.y = fmaf(A1.y, p1, fmaf(A1.w, q1, a1.y));
            }
            {
                float4 A0 = sAB[m0.z * 16 + c], A1 = sAB[m1.z * 16 + c];
                float p0 = __uint_as_float(m0.x), q0 = __uint_as_float(m0.y);
                float p1 = __uint_as_float(m1.x), q1 = __uint_as_float(m1.y);
                a0.x = fmaf(A0.x, p0, fmaf(A0.z, q0, a0.x));
                a0.y = fmaf(A0.y, p0, fmaf(A0.w, q0, a0.y));
                a1.x = fmaf(A1.x, p1, fmaf(A1.z, q1, a1.x));
                a1.y = fmaf(A1.y, p1, fmaf(A1.w, q1, a1.y));
            }
        } else if (P == 1) {
            uint4 r0 = recs[csr[o]], r1 = recs[csr[o + 1]];
            float4 A0 = sAB[r0.z * 16 + c], A1 = sAB[r1.z * 16 + c];
            float p0 = __uint_as_float(r0.x), q0 = __uint_as_float(r0.y);
            float p1 = __uint_as_float(r1.x), q1 = __uint_as_float(r1.y);
            a0.x = fmaf(A0.x, p0, fmaf(A0.z, q0, a0.x));
            a0.y = fmaf(A0.y, p0, fmaf(A0.w, q0, a0.y));
            a1.x = fmaf(A1.x, p1, fmaf(A1.z, q1, a1.x));
            a1.y = fmaf(A1.y, p1, fmaf(A1.w, q1, a1.y));
        }
        if (n & 1u) {                          // odd tail
            uint4 r0 = recs[csr[o + n - 1]];
            float4 A0 = sAB[r0.z * 16 + c];
            float p0 = __uint_as_float(r0.x), q0 = __uint_as_float(r0.y);
            a0.x = fmaf(A0.x, p0, fmaf(A0.z, q0, a0.x));
            a0.y = fmaf(A0.y, p0, fmaf(A0.w, q0, a0.y));
        }
        float hx = fmaxf(fmaf(dd, a0.x + a1.x, sb2[c]), 0.f);        // h2[c]
        float hy = fmaxf(fmaf(dd, a0.y + a1.y, sb2[c + 16]), 0.f);   // h2[c+16]

        // in-register W3 transform: t3[c] = sum_k h2[k] * W3[k][c]
        float t3 = 0.f;
#pragma unroll
        for (int kk = 0; kk < 16; ++kk) {
            float hk = __shfl(hx, kk, 16);
            t3 = fmaf(hk, sW3[kk * 16 + c], t3);
        }
#pragma unroll
        for (int kk = 0; kk < 16; ++kk) {
            float hk = __shfl(hy, kk, 16);
            t3 = fmaf(hk, sW3[(kk + 16) * 16 + c], t3);
        }
        tt3[(size_t)d * 16 + c] = dd * t3;
    }
}

// ---------------- layer-3 gather (float4, 4 lanes/node, csr 1-quad ahead) -> tt4 ----------------
__global__ __launch_bounds__(256) void gather3t4_kernel(const unsigned int* __restrict__ csr,
                                                        const unsigned int* __restrict__ off,
                                                        const unsigned int* __restrict__ deg,
                                                        const float* __restrict__ dinv,
                                                        const float* __restrict__ tt3,
                                                        const float* __restrict__ b3, const float* __restrict__ W4,
                                                        float* __restrict__ tt4, int N) {
    int tid = blockIdx.x * 256 + threadIdx.x;
    int d = tid >> 2, l = tid & 3;
    if (d >= N) return;
    float dd = dinv[d];
    unsigned int o = off[d], n = deg[d];
    const float4* t34 = reinterpret_cast<const float4*>(tt3);
    float4 acc = t34[(size_t)d * 4 + l];   // self term
    float4 acc1 = make_float4(0.f, 0.f, 0.f, 0.f);
    unsigned int k = 0;
    if (n >= 4) {
        unsigned int s0 = csr[o], s1 = csr[o + 1], s2 = csr[o + 2], s3 = csr[o + 3];
        k = 4;
        for (; k + 3 < n; k += 4) {
            unsigned int t0 = csr[o + k], t1 = csr[o + k + 1], t2 = csr[o + k + 2], t3 = csr[o + k + 3];
            float4 v0 = t34[(size_t)s0 * 4 + l];
            float4 v1 = t34[(size_t)s1 * 4 + l];
            float4 v2 = t34[(size_t)s2 * 4 + l];
            float4 v3 = t34[(size_t)s3 * 4 + l];
            acc.x += v0.x + v2.x; acc.y += v0.y + v2.y; acc.z += v0.z + v2.z; acc.w += v0.w + v2.w;
            acc1.x += v1.x + v3.x; acc1.y += v1.y + v3.y; acc1.z += v1.z + v3.z; acc1.w += v1.w + v3.w;
            s0 = t0; s1 = t1; s2 = t2; s3 = t3;
        }
        {   // drain in-flight quad
            float4 v0 = t34[(size_t)s0 * 4 + l];
            float4 v1 = t34[(size_t)s1 * 4 + l];
            float4 v2 = t34[(size_t)s2 * 4 + l];
            float4 v3 = t34[(size_t)s3 * 4 + l];
            acc.x += v0.x + v2.x; acc.y += v0.y + v2.y; acc.z += v0.z + v2.z; acc.w += v0.w + v2.w;
            acc1.x += v1.x + v3.x; acc1.y += v1.y + v3.y; acc1.z += v1.z + v3.z; acc1.w += v1.w + v3.w;
        }
    }
    for (; k < n; ++k) {
        float4 v0 = t34[(size_t)csr[o + k] * 4 + l];
        acc.x += v0.x; acc.y += v0.y; acc.z += v0.z; acc.w += v0.w;
    }
    acc.x += acc1.x; acc.y += acc1.y; acc.z += acc1.z; acc.w += acc1.w;
    float4 b3v = reinterpret_cast<const float4*>(b3)[l];
    float4 w4v = reinterpret_cast<const float4*>(W4)[l];
    float v = fmaxf(fmaf(dd, acc.x, b3v.x), 0.f) * w4v.x;
    v = fmaf(fmaxf(fmaf(dd, acc.y, b3v.y), 0.f), w4v.y, v);
    v = fmaf(fmaxf(fmaf(dd, acc.z, b3v.z), 0.f), w4v.z, v);
    v = fmaf(fmaxf(fmaf(dd, acc.w, b3v.w), 0.f), w4v.w, v);
    v += __shfl_xor(v, 1, 4);
    v += __shfl_xor(v, 2, 4);
    if (l == 0) tt4[d] = dd * v;
}

// ---------------- layer-4 scalar gather -> out ----------------
__global__ void gather4_kernel(const unsigned int* __restrict__ csr, const unsigned int* __restrict__ off,
                               const unsigned int* __restrict__ deg, const float* __restrict__ dinv,
                               const float* __restrict__ tt, const float* __restrict__ b4,
                               float* __restrict__ out, int N) {
    int tid = blockIdx.x * blockDim.x + threadIdx.x;
    int i = tid >> 2, l = tid & 3;
    if (i >= N) return;
    unsigned int o = off[i], n = deg[i];
    float acc0 = 0.f, acc1 = 0.f;
    unsigned int k = l;
    for (; k + 4 < n; k += 8) { acc0 += tt[csr[o + k]]; acc1 += tt[csr[o + k + 4]]; }
    if (k < n) acc0 += tt[csr[o + k]];
    float acc = acc0 + acc1;
    acc += __shfl_xor(acc, 1, 4);
    acc += __shfl_xor(acc, 2, 4);
    if (l == 0) out[i] = dinv[i] * (acc + tt[i]) + b4[0];
}

extern "C" void kernel_launch(void* const* d_in, const int* in_sizes, int n_in,
                              void* d_out, int out_size, void* d_ws, size_t ws_size,
                              hipStream_t stream) {
    const float* x  = (const float*)d_in[0];
    const int* eidx = (const int*)d_in[1];
    const float* W1 = (const float*)d_in[2];
    const float* b1 = (const float*)d_in[3];
    const float* W2 = (const float*)d_in[4];
    const float* b2 = (const float*)d_in[5];
    const float* W3 = (const float*)d_in[6];
    const float* b3 = (const float*)d_in[7];
    const float* W4 = (const float*)d_in[8];
    const float* b4 = (const float*)d_in[9];
    float* out = (float*)d_out;

    const int N = in_sizes[0];         // 100000
    const int E = in_sizes[1] / 2;     // 3200000
    const int* src = eidx;
    const int* dst = eidx + E;
    const int NB = (N + NPB - 1) >> NPB_SHIFT;   // 391 buckets

    char* ws = (char*)d_ws;
    unsigned int* bcur  = (unsigned int*)ws;  ws += MAXB * 4;
    float* tvals = (float*)ws;                ws += 64 * 4;
    float* Alut  = (float*)ws;                ws += 65 * 32 * 4;
    float* Blut  = (float*)ws;                ws += 65 * 32 * 4;
    unsigned int* off = (unsigned int*)ws;    ws += (size_t)N * 4;
    unsigned int* deg = (unsigned int*)ws;    ws += (size_t)N * 4;
    float* dinv = (float*)ws;                 ws += (size_t)N * 4;
    float* ttx  = (float*)ws;                 ws += (size_t)N * 4;
    float* tt4  = (float*)ws;                 ws += (size_t)N * 4;
    uint4* recs = (uint4*)ws;                 ws += (size_t)N * 16;
    unsigned int* csr = (unsigned int*)ws;    ws += (size_t)NB * BCAP * 4;   // padded CSR (14.4MB)
    unsigned int* staged = (unsigned int*)ws; // padded staged; tt3 (6.4MB) aliases it
    float* tt3 = (float*)staged;              // staged dead after build_csr

    const int nPartBlocks = (E + EPB - 1) / EPB;   // 521

    bcur_init_kernel<<<(NB + 255) / 256, 256, 0, stream>>>(bcur, NB);
    partition_kernel<<<nPartBlocks, 256, 0, stream>>>(src, dst, bcur, staged, E, NB);
    build_csr_kernel<<<NB, 256, 0, stream>>>(staged, bcur, x, csr, off, deg, dinv, ttx, N);
    lut_kernel<<<65, 256, 0, stream>>>(W1, b1, W2, Alut, Blut, tvals);

    gather1_kernel<<<((size_t)N * 4 + 255) / 256, 256, 0, stream>>>(csr, off, deg, dinv, ttx, tvals, recs, N);
    gather2t3_kernel<<<(N + G2_NODES - 1) / G2_NODES, 256, 0, stream>>>(csr, off, deg, dinv, recs, Alut, Blut, b2, W3, tt3, N);
    gather3t4_kernel<<<((size_t)N * 4 + 255) / 256, 256, 0, stream>>>(csr, off, deg, dinv, tt3, b3, W4, tt4, N);
    gather4_kernel<<<((size_t)N * 4 + 255) / 256, 256, 0, stream>>>(csr, off, deg, dinv, tt4, b4, out, N);
}

// Round 15
// 194.086 us; speedup vs baseline: 1.1742x; 1.0781x over previous
//
#include <hip/hip_runtime.h>

#define NPB_SHIFT 8
#define NPB 256          // nodes per bucket
#define EPB 6144         // edges per partition block (521 blocks -> >=2/CU)
#define MAXB 512         // padded bucket count (NB = ceil(100000/256) = 391)
#define BCAP 9216        // fixed bucket capacity: E/NB=8184, sigma~90 -> +11 sigma
#define SRC_BITS 17      // N=100000 < 2^17
#define SRC_MASK 0x1FFFFu

// ---------------- K3: LDS-staged partition, packed u32 records ----------------
__global__ __launch_bounds__(256) void partition_kernel(const int* __restrict__ src,
                                                        const int* __restrict__ dst,
                                                        unsigned int* __restrict__ bcur,
                                                        unsigned int* __restrict__ staged, int E, int NB) {
    __shared__ unsigned int hist[MAXB], sc[MAXB], lbase[MAXB], lcur[MAXB], gbase[MAXB];
    __shared__ unsigned int stage[EPB];
    __shared__ unsigned short sbuck[EPB];
    int start = blockIdx.x * EPB;
    int cnt = min(EPB, E - start);
    for (int j = threadIdx.x; j < MAXB; j += 256) hist[j] = 0u;
    __syncthreads();
    for (int k = threadIdx.x; k < cnt; k += 256)
        atomicAdd(&hist[((unsigned int)dst[start + k]) >> NPB_SHIFT], 1u);
    __syncthreads();
    {
        int i0 = threadIdx.x, i1 = threadIdx.x + 256;
        sc[i0] = hist[i0]; sc[i1] = hist[i1];
        __syncthreads();
        for (int o = 1; o < MAXB; o <<= 1) {
            unsigned int v0 = (i0 >= o) ? sc[i0 - o] : 0u;
            unsigned int v1 = (i1 >= o) ? sc[i1 - o] : 0u;
            __syncthreads();
            sc[i0] += v0; sc[i1] += v1;
            __syncthreads();
        }
    }
    for (int j = threadIdx.x; j < MAXB; j += 256) {
        unsigned int c = hist[j];
        unsigned int ex = sc[j] - c;
        lbase[j] = ex; lcur[j] = ex;
        gbase[j] = (j < NB && c) ? atomicAdd(&bcur[j], c) : 0u;
    }
    __syncthreads();
    for (int k = threadIdx.x; k < cnt; k += 256) {
        unsigned int d = (unsigned int)dst[start + k];
        unsigned int b = d >> NPB_SHIFT;
        unsigned int pos = atomicAdd(&lcur[b], 1u);
        stage[pos] = ((d & (NPB - 1)) << SRC_BITS) | (unsigned int)src[start + k];
        sbuck[pos] = (unsigned short)b;
    }
    __syncthreads();
    for (int t = threadIdx.x; t < cnt; t += 256) {
        unsigned int b = sbuck[t];
        staged[(size_t)gbase[b] + (t - lbase[b])] = stage[t];
    }
}

// ---------------- K4: per-bucket exact CSR + off/deg/dinv/ttx ----------------
__global__ __launch_bounds__(256) void build_csr_kernel(const unsigned int* __restrict__ staged,
                                                        const unsigned int* __restrict__ bcur,
                                                        const float* __restrict__ x,
                                                        unsigned int* __restrict__ csr,
                                                        unsigned int* __restrict__ off,
                                                        unsigned int* __restrict__ deg,
                                                        float* __restrict__ dinv,
                                                        float* __restrict__ ttx, int N) {
    __shared__ unsigned int cnt[NPB], loff[NPB], ncur[NPB];
    int b = blockIdx.x;
    unsigned int base = (unsigned int)b * BCAP;
    unsigned int m = bcur[b] - base;
    int node0 = b << NPB_SHIFT;
    cnt[threadIdx.x] = 0u;
    __syncthreads();
    for (unsigned int t = threadIdx.x; t < m; t += 256)
        atomicAdd(&cnt[staged[(size_t)base + t] >> SRC_BITS], 1u);
    __syncthreads();
    unsigned int v = cnt[threadIdx.x];
    loff[threadIdx.x] = v;
    __syncthreads();
    for (int o = 1; o < NPB; o <<= 1) {
        unsigned int a = (threadIdx.x >= (unsigned)o) ? loff[threadIdx.x - o] : 0u;
        __syncthreads();
        loff[threadIdx.x] += a;
        __syncthreads();
    }
    unsigned int ex = loff[threadIdx.x] - v;
    ncur[threadIdx.x] = ex;
    int node = node0 + threadIdx.x;
    if (node < N) {
        off[node] = base + ex;
        deg[node] = v;
        float di = 1.0f / sqrtf((float)(v + 1u));  // +1 self loop
        dinv[node] = di;
        ttx[node] = di * x[node];
    }
    __syncthreads();
    for (unsigned int t = threadIdx.x; t < m; t += 256) {
        unsigned int rec = staged[(size_t)base + t];
        unsigned int p = atomicAdd(&ncur[rec >> SRC_BITS], 1u);
        csr[(size_t)base + p] = rec & SRC_MASK;
    }
}

// ---------------- LUT build (65 blocks); block 0 also inits bcur ----------------
__global__ __launch_bounds__(256) void lut_kernel(const float* __restrict__ W1, const float* __restrict__ b1,
                                                  const float* __restrict__ W2,
                                                  float* __restrict__ Alut, float* __restrict__ Blut,
                                                  float* __restrict__ tvals,
                                                  unsigned int* __restrict__ bcur, int NB) {
    __shared__ float w1[64], bb[64], tv[64];
    __shared__ int rnk[64];
    __shared__ float sW2[64 * 32];
    __shared__ double red[2][256];
    int tid = threadIdx.x;
    if (blockIdx.x == 0) {
        for (int t = tid; t < NB; t += 256) bcur[t] = (unsigned int)t * BCAP;
    }
    if (tid < 64) {
        float w = W1[tid], b = b1[tid];
        w1[tid] = w; bb[tid] = b;
        tv[tid] = (w != 0.f) ? (-b / w) : __uint_as_float(0x7F800000u);  // +inf for degenerate
    }
    for (int t = tid; t < 64 * 32; t += 256) sW2[t] = W2[t];
    __syncthreads();
    if (tid < 64) {
        int r = 0;
        float tj = tv[tid];
        for (int k = 0; k < 64; ++k)
            if (w1[k] != 0.f && (tv[k] < tj || (tv[k] == tj && k < tid))) ++r;
        rnk[tid] = r;
        if (blockIdx.x == 0) tvals[tid] = tv[tid];
    }
    __syncthreads();
    int s = blockIdx.x;                 // segment 0..64
    int c = tid & 31, slice = tid >> 5; // 8 j-slices x 32 channels
    double da = 0.0, db = 0.0;
#pragma unroll
    for (int u = 0; u < 8; ++u) {
        int j = slice * 8 + u;
        float w = w1[j];
        bool act = (w > 0.f) ? (rnk[j] < s) : ((w < 0.f) ? (rnk[j] >= s) : (bb[j] > 0.f));
        if (act) {
            double w2 = (double)sW2[j * 32 + c];
            da += (double)w * w2;
            db += (double)bb[j] * w2;
        }
    }
    red[0][tid] = da; red[1][tid] = db;
    __syncthreads();
    for (int o = 128; o >= 32; o >>= 1) {
        if (tid < o) { red[0][tid] += red[0][tid + o]; red[1][tid] += red[1][tid + o]; }
        __syncthreads();
    }
    if (tid < 32) {
        Alut[s * 32 + tid] = (float)red[0][tid];
        Blut[s * 32 + tid] = (float)red[1][tid];
    }
}

// ---------------- layer-1 gather + fused segment classification -> recs ----------------
__global__ __launch_bounds__(256) void gather1_kernel(const unsigned int* __restrict__ csr,
                                                      const unsigned int* __restrict__ off,
                                                      const unsigned int* __restrict__ deg,
                                                      const float* __restrict__ dinv,
                                                      const float* __restrict__ tt,
                                                      const float* __restrict__ tvals,
                                                      uint4* __restrict__ recs, int N) {
    __shared__ float st[64];
    for (int t = threadIdx.x; t < 64; t += 256) st[t] = tvals[t];
    __syncthreads();
    int tid = blockIdx.x * 256 + threadIdx.x;
    int i = tid >> 2, l = tid & 3;
    if (i >= N) return;
    unsigned int o = off[i], n = deg[i];
    float acc0 = 0.f, acc1 = 0.f;
    unsigned int k = l;
    for (; k + 4 < n; k += 8) { acc0 += tt[csr[o + k]]; acc1 += tt[csr[o + k + 4]]; }
    if (k < n) acc0 += tt[csr[o + k]];
    float acc = acc0 + acc1;
    acc += __shfl_xor(acc, 1, 4);
    acc += __shfl_xor(acc, 2, 4);
    float di = dinv[i];
    float a = di * (acc + tt[i]);        // agg1 (all 4 lanes hold it)
    unsigned int cv = 0;
#pragma unroll
    for (int j = 0; j < 16; ++j) cv += (st[l * 16 + j] < a) ? 1u : 0u;
    cv += __shfl_xor(cv, 1, 4);
    cv += __shfl_xor(cv, 2, 4);
    if (l == 0) recs[i] = make_uint4(__float_as_uint(a * di), __float_as_uint(di), cv, 0u);
}

// ---------------- layer-2 LUT gather + in-register shuffle transform -> tt3 ----------------
// 8 lanes/node (lane owns channels cc, cc+8, cc+16, cc+24): 8 groups/wave ->
// 2x independent load streams vs 16-lane version. 2-stage rotating pipeline kept.
#define G2_ITERS 4
#define FMA4(R, ACC)                                                          \
    {                                                                         \
        float4 A_ = sA2[(R).z * 8 + cc], B_ = sB2[(R).z * 8 + cc];            \
        float p_ = __uint_as_float((R).x), q_ = __uint_as_float((R).y);       \
        (ACC).x = fmaf(A_.x, p_, fmaf(B_.x, q_, (ACC).x));                    \
        (ACC).y = fmaf(A_.y, p_, fmaf(B_.y, q_, (ACC).y));                    \
        (ACC).z = fmaf(A_.z, p_, fmaf(B_.z, q_, (ACC).z));                    \
        (ACC).w = fmaf(A_.w, p_, fmaf(B_.w, q_, (ACC).w));                    \
    }
__global__ __launch_bounds__(256) void gather2t3_kernel(const unsigned int* __restrict__ csr,
                                                        const unsigned int* __restrict__ off,
                                                        const unsigned int* __restrict__ deg,
                                                        const float* __restrict__ dinv,
                                                        const uint4* __restrict__ recs,
                                                        const float* __restrict__ Alut, const float* __restrict__ Blut,
                                                        const float* __restrict__ b2, const float* __restrict__ W3,
                                                        float* __restrict__ tt3, int N) {
    __shared__ float4 sA2[65 * 8], sB2[65 * 8];
    __shared__ float2 sW3p[32 * 8];
    __shared__ float sb2[32];
    for (int t = threadIdx.x; t < 65 * 8; t += 256) {
        int s = t >> 3, q = t & 7;
        sA2[t] = make_float4(Alut[s * 32 + q], Alut[s * 32 + q + 8],
                             Alut[s * 32 + q + 16], Alut[s * 32 + q + 24]);
        sB2[t] = make_float4(Blut[s * 32 + q], Blut[s * 32 + q + 8],
                             Blut[s * 32 + q + 16], Blut[s * 32 + q + 24]);
    }
    for (int t = threadIdx.x; t < 32 * 8; t += 256) {
        int k = t >> 3, q = t & 7;
        sW3p[t] = make_float2(W3[k * 16 + q], W3[k * 16 + q + 8]);
    }
    if (threadIdx.x < 32) sb2[threadIdx.x] = b2[threadIdx.x];
    __syncthreads();

    int g = threadIdx.x >> 3, cc = threadIdx.x & 7;
    for (int iter = 0; iter < G2_ITERS; ++iter) {
        int d = blockIdx.x * (32 * G2_ITERS) + iter * 32 + g;
        if (d >= N) continue;                 // uniform within the 8-lane group
        float dd = dinv[d];
        unsigned int o = off[d], n = deg[d];
        uint4 rs = recs[d];
        float ps = __uint_as_float(rs.x), qs = __uint_as_float(rs.y);
        float4 As = sA2[rs.z * 8 + cc], Bs = sB2[rs.z * 8 + cc];
        float4 aP, aQ;
        aP.x = fmaf(As.x, ps, Bs.x * qs); aP.y = fmaf(As.y, ps, Bs.y * qs);
        aP.z = fmaf(As.z, ps, Bs.z * qs); aP.w = fmaf(As.w, ps, Bs.w * qs);
        aQ = make_float4(0.f, 0.f, 0.f, 0.f);
        unsigned int P = n >> 1;
        if (P >= 2) {
            unsigned int c0 = csr[o], c1 = csr[o + 1];
            unsigned int c2 = csr[o + 2], c3 = csr[o + 3];
            uint4 r0 = recs[c0], r1 = recs[c1];
            for (unsigned int j = 0; j + 2 < P; ++j) {
                unsigned int base = o + 2 * j;
                unsigned int nc0 = csr[base + 4], nc1 = csr[base + 5];  // csr pair j+2
                uint4 nr0 = recs[c2], nr1 = recs[c3];                   // recs pair j+1
                FMA4(r0, aP); FMA4(r1, aQ);                             // FMA pair j
                r0 = nr0; r1 = nr1; c2 = nc0; c3 = nc1;
            }
            uint4 m0 = recs[c2], m1 = recs[c3];
            FMA4(r0, aP); FMA4(r1, aQ);
            FMA4(m0, aP); FMA4(m1, aQ);
        } else if (P == 1) {
            uint4 r0 = recs[csr[o]], r1 = recs[csr[o + 1]];
            FMA4(r0, aP); FMA4(r1, aQ);
        }
        if (n & 1u) {
            uint4 r0 = recs[csr[o + n - 1]];
            FMA4(r0, aP);
        }
        float hv0 = fmaxf(fmaf(dd, aP.x + aQ.x, sb2[cc]), 0.f);
        float hv1 = fmaxf(fmaf(dd, aP.y + aQ.y, sb2[cc + 8]), 0.f);
        float hv2 = fmaxf(fmaf(dd, aP.z + aQ.z, sb2[cc + 16]), 0.f);
        float hv3 = fmaxf(fmaf(dd, aP.w + aQ.w, sb2[cc + 24]), 0.f);

        // in-register W3 transform: t3[c] = sum_k h2[k]*W3[k][c], c in {cc, cc+8}
        float t0 = 0.f, t1 = 0.f;
#pragma unroll
        for (int l2 = 0; l2 < 8; ++l2) {
            float hk = __shfl(hv0, l2, 8);
            float2 w = sW3p[l2 * 8 + cc];
            t0 = fmaf(hk, w.x, t0); t1 = fmaf(hk, w.y, t1);
        }
#pragma unroll
        for (int l2 = 0; l2 < 8; ++l2) {
            float hk = __shfl(hv1, l2, 8);
            float2 w = sW3p[(8 + l2) * 8 + cc];
            t0 = fmaf(hk, w.x, t0); t1 = fmaf(hk, w.y, t1);
        }
#pragma unroll
        for (int l2 = 0; l2 < 8; ++l2) {
            float hk = __shfl(hv2, l2, 8);
            float2 w = sW3p[(16 + l2) * 8 + cc];
            t0 = fmaf(hk, w.x, t0); t1 = fmaf(hk, w.y, t1);
        }
#pragma unroll
        for (int l2 = 0; l2 < 8; ++l2) {
            float hk = __shfl(hv3, l2, 8);
            float2 w = sW3p[(24 + l2) * 8 + cc];
            t0 = fmaf(hk, w.x, t0); t1 = fmaf(hk, w.y, t1);
        }
        tt3[(size_t)d * 16 + cc] = dd * t0;
        tt3[(size_t)d * 16 + cc + 8] = dd * t1;
    }
}

// ---------------- layer-3 gather (float4, 4 lanes/node, csr 1-quad ahead) -> tt4 ----------------
__global__ __launch_bounds__(256) void gather3t4_kernel(const unsigned int* __restrict__ csr,
                                                        const unsigned int* __restrict__ off,
                                                        const unsigned int* __restrict__ deg,
                                                        const float* __restrict__ dinv,
                                                        const float* __restrict__ tt3,
                                                        const float* __restrict__ b3, const float* __restrict__ W4,
                                                        float* __restrict__ tt4, int N) {
    int tid = blockIdx.x * 256 + threadIdx.x;
    int d = tid >> 2, l = tid & 3;
    if (d >= N) return;
    float dd = dinv[d];
    unsigned int o = off[d], n = deg[d];
    const float4* t34 = reinterpret_cast<const float4*>(tt3);
    float4 acc = t34[(size_t)d * 4 + l];   // self term
    float4 acc1 = make_float4(0.f, 0.f, 0.f, 0.f);
    unsigned int k = 0;
    if (n >= 4) {
        unsigned int s0 = csr[o], s1 = csr[o + 1], s2 = csr[o + 2], s3 = csr[o + 3];
        k = 4;
        for (; k + 3 < n; k += 4) {
            unsigned int t0 = csr[o + k], t1 = csr[o + k + 1], t2 = csr[o + k + 2], t3 = csr[o + k + 3];
            float4 v0 = t34[(size_t)s0 * 4 + l];
            float4 v1 = t34[(size_t)s1 * 4 + l];
            float4 v2 = t34[(size_t)s2 * 4 + l];
            float4 v3 = t34[(size_t)s3 * 4 + l];
            acc.x += v0.x + v2.x; acc.y += v0.y + v2.y; acc.z += v0.z + v2.z; acc.w += v0.w + v2.w;
            acc1.x += v1.x + v3.x; acc1.y += v1.y + v3.y; acc1.z += v1.z + v3.z; acc1.w += v1.w + v3.w;
            s0 = t0; s1 = t1; s2 = t2; s3 = t3;
        }
        {   // drain in-flight quad
            float4 v0 = t34[(size_t)s0 * 4 + l];
            float4 v1 = t34[(size_t)s1 * 4 + l];
            float4 v2 = t34[(size_t)s2 * 4 + l];
            float4 v3 = t34[(size_t)s3 * 4 + l];
            acc.x += v0.x + v2.x; acc.y += v0.y + v2.y; acc.z += v0.z + v2.z; acc.w += v0.w + v2.w;
            acc1.x += v1.x + v3.x; acc1.y += v1.y + v3.y; acc1.z += v1.z + v3.z; acc1.w += v1.w + v3.w;
        }
    }
    for (; k < n; ++k) {
        float4 v0 = t34[(size_t)csr[o + k] * 4 + l];
        acc.x += v0.x; acc.y += v0.y; acc.z += v0.z; acc.w += v0.w;
    }
    acc.x += acc1.x; acc.y += acc1.y; acc.z += acc1.z; acc.w += acc1.w;
    float4 b3v = reinterpret_cast<const float4*>(b3)[l];
    float4 w4v = reinterpret_cast<const float4*>(W4)[l];
    float v = fmaxf(fmaf(dd, acc.x, b3v.x), 0.f) * w4v.x;
    v = fmaf(fmaxf(fmaf(dd, acc.y, b3v.y), 0.f), w4v.y, v);
    v = fmaf(fmaxf(fmaf(dd, acc.z, b3v.z), 0.f), w4v.z, v);
    v = fmaf(fmaxf(fmaf(dd, acc.w, b3v.w), 0.f), w4v.w, v);
    v += __shfl_xor(v, 1, 4);
    v += __shfl_xor(v, 2, 4);
    if (l == 0) tt4[d] = dd * v;
}

// ---------------- layer-4 scalar gather -> out ----------------
__global__ void gather4_kernel(const unsigned int* __restrict__ csr, const unsigned int* __restrict__ off,
                               const unsigned int* __restrict__ deg, const float* __restrict__ dinv,
                               const float* __restrict__ tt, const float* __restrict__ b4,
                               float* __restrict__ out, int N) {
    int tid = blockIdx.x * blockDim.x + threadIdx.x;
    int i = tid >> 2, l = tid & 3;
    if (i >= N) return;
    unsigned int o = off[i], n = deg[i];
    float acc0 = 0.f, acc1 = 0.f;
    unsigned int k = l;
    for (; k + 4 < n; k += 8) { acc0 += tt[csr[o + k]]; acc1 += tt[csr[o + k + 4]]; }
    if (k < n) acc0 += tt[csr[o + k]];
    float acc = acc0 + acc1;
    acc += __shfl_xor(acc, 1, 4);
    acc += __shfl_xor(acc, 2, 4);
    if (l == 0) out[i] = dinv[i] * (acc + tt[i]) + b4[0];
}

extern "C" void kernel_launch(void* const* d_in, const int* in_sizes, int n_in,
                              void* d_out, int out_size, void* d_ws, size_t ws_size,
                              hipStream_t stream) {
    const float* x  = (const float*)d_in[0];
    const int* eidx = (const int*)d_in[1];
    const float* W1 = (const float*)d_in[2];
    const float* b1 = (const float*)d_in[3];
    const float* W2 = (const float*)d_in[4];
    const float* b2 = (const float*)d_in[5];
    const float* W3 = (const float*)d_in[6];
    const float* b3 = (const float*)d_in[7];
    const float* W4 = (const float*)d_in[8];
    const float* b4 = (const float*)d_in[9];
    float* out = (float*)d_out;

    const int N = in_sizes[0];         // 100000
    const int E = in_sizes[1] / 2;     // 3200000
    const int* src = eidx;
    const int* dst = eidx + E;
    const int NB = (N + NPB - 1) >> NPB_SHIFT;   // 391 buckets

    char* ws = (char*)d_ws;
    unsigned int* bcur  = (unsigned int*)ws;  ws += MAXB * 4;
    float* tvals = (float*)ws;                ws += 64 * 4;
    float* Alut  = (float*)ws;                ws += 65 * 32 * 4;
    float* Blut  = (float*)ws;                ws += 65 * 32 * 4;
    unsigned int* off = (unsigned int*)ws;    ws += (size_t)N * 4;
    unsigned int* deg = (unsigned int*)ws;    ws += (size_t)N * 4;
    float* dinv = (float*)ws;                 ws += (size_t)N * 4;
    float* ttx  = (float*)ws;                 ws += (size_t)N * 4;
    float* tt4  = (float*)ws;                 ws += (size_t)N * 4;
    uint4* recs = (uint4*)ws;                 ws += (size_t)N * 16;
    unsigned int* csr = (unsigned int*)ws;    ws += (size_t)NB * BCAP * 4;   // padded CSR (14.4MB)
    unsigned int* staged = (unsigned int*)ws; // padded staged; tt3 (6.4MB) aliases it
    float* tt3 = (float*)staged;              // staged dead after build_csr

    const int nPartBlocks = (E + EPB - 1) / EPB;   // 521

    lut_kernel<<<65, 256, 0, stream>>>(W1, b1, W2, Alut, Blut, tvals, bcur, NB);
    partition_kernel<<<nPartBlocks, 256, 0, stream>>>(src, dst, bcur, staged, E, NB);
    build_csr_kernel<<<NB, 256, 0, stream>>>(staged, bcur, x, csr, off, deg, dinv, ttx, N);

    gather1_kernel<<<((size_t)N * 4 + 255) / 256, 256, 0, stream>>>(csr, off, deg, dinv, ttx, tvals, recs, N);
    gather2t3_kernel<<<(N + 32 * G2_ITERS - 1) / (32 * G2_ITERS), 256, 0, stream>>>(csr, off, deg, dinv, recs, Alut, Blut, b2, W3, tt3, N);
    gather3t4_kernel<<<((size_t)N * 4 + 255) / 256, 256, 0, stream>>>(csr, off, deg, dinv, tt3, b3, W4, tt4, N);
    gather4_kernel<<<((size_t)N * 4 + 255) / 256, 256, 0, stream>>>(csr, off, deg, dinv, tt4, b4, out, N);
}

// Round 16
// 188.769 us; speedup vs baseline: 1.2073x; 1.0282x over previous
//
#include <hip/hip_runtime.h>

#define NPB_SHIFT 8
#define NPB 256          // nodes per bucket
#define EPB 4096         // edges per partition block (782 blocks, 32KB LDS -> 5 blocks/CU)
#define EPT 16           // edges per thread in partition (EPB/256)
#define MAXB 512         // padded bucket count (NB = ceil(100000/256) = 391)
#define BCAP 9216        // fixed bucket capacity: E/NB=8184, sigma~90 -> +11 sigma
#define SRC_BITS 17      // N=100000 < 2^17
#define SRC_MASK 0x1FFFFu

// ---------------- K3: single-pass LDS-staged partition (register-held ranks) ----------------
__global__ __launch_bounds__(256) void partition_kernel(const int* __restrict__ src,
                                                        const int* __restrict__ dst,
                                                        unsigned int* __restrict__ bcur,
                                                        unsigned int* __restrict__ staged, int E, int NB) {
    __shared__ unsigned int hist[MAXB], sc[MAXB], lbase[MAXB], gbase[MAXB];
    __shared__ unsigned int stage[EPB];
    __shared__ unsigned short sbuck[EPB];
    int start = blockIdx.x * EPB;
    int cnt = min(EPB, E - start);
    for (int j = threadIdx.x; j < MAXB; j += 256) hist[j] = 0u;
    __syncthreads();

    unsigned int rec[EPT], rnk[EPT], bkt[EPT];
#pragma unroll
    for (int u = 0; u < EPT; ++u) {
        int k = u * 256 + threadIdx.x;
        if (k < cnt) {
            unsigned int d = (unsigned int)dst[start + k];
            unsigned int s = (unsigned int)src[start + k];
            unsigned int b = d >> NPB_SHIFT;
            rec[u] = ((d & (NPB - 1)) << SRC_BITS) | s;
            bkt[u] = b;
            rnk[u] = atomicAdd(&hist[b], 1u);   // in-bucket rank, single pass
        }
    }
    __syncthreads();
    // inclusive scan of hist (512 entries, 2 per thread)
    {
        int i0 = threadIdx.x, i1 = threadIdx.x + 256;
        sc[i0] = hist[i0]; sc[i1] = hist[i1];
        __syncthreads();
        for (int o = 1; o < MAXB; o <<= 1) {
            unsigned int v0 = (i0 >= o) ? sc[i0 - o] : 0u;
            unsigned int v1 = (i1 >= o) ? sc[i1 - o] : 0u;
            __syncthreads();
            sc[i0] += v0; sc[i1] += v1;
            __syncthreads();
        }
    }
    for (int j = threadIdx.x; j < MAXB; j += 256) {
        unsigned int c = hist[j];
        lbase[j] = sc[j] - c;
        gbase[j] = (j < NB && c) ? atomicAdd(&bcur[j], c) : 0u;
    }
    __syncthreads();
    // place records into LDS, bucket-grouped (no second global read, no lcur atomics)
#pragma unroll
    for (int u = 0; u < EPT; ++u) {
        int k = u * 256 + threadIdx.x;
        if (k < cnt) {
            unsigned int pos = lbase[bkt[u]] + rnk[u];
            stage[pos] = rec[u];
            sbuck[pos] = (unsigned short)bkt[u];
        }
    }
    __syncthreads();
    // coalesced copy-out: consecutive LDS slots -> consecutive global slots per bucket
    for (int t = threadIdx.x; t < cnt; t += 256) {
        unsigned int b = sbuck[t];
        staged[(size_t)gbase[b] + (t - lbase[b])] = stage[t];
    }
}

// ---------------- K4: per-bucket exact CSR + off/deg/dinv/ttx ----------------
__global__ __launch_bounds__(256) void build_csr_kernel(const unsigned int* __restrict__ staged,
                                                        const unsigned int* __restrict__ bcur,
                                                        const float* __restrict__ x,
                                                        unsigned int* __restrict__ csr,
                                                        unsigned int* __restrict__ off,
                                                        unsigned int* __restrict__ deg,
                                                        float* __restrict__ dinv,
                                                        float* __restrict__ ttx, int N) {
    __shared__ unsigned int cnt[NPB], loff[NPB], ncur[NPB];
    int b = blockIdx.x;
    unsigned int base = (unsigned int)b * BCAP;
    unsigned int m = bcur[b] - base;
    int node0 = b << NPB_SHIFT;
    cnt[threadIdx.x] = 0u;
    __syncthreads();
    for (unsigned int t = threadIdx.x; t < m; t += 256)
        atomicAdd(&cnt[staged[(size_t)base + t] >> SRC_BITS], 1u);
    __syncthreads();
    unsigned int v = cnt[threadIdx.x];
    loff[threadIdx.x] = v;
    __syncthreads();
    for (int o = 1; o < NPB; o <<= 1) {
        unsigned int a = (threadIdx.x >= (unsigned)o) ? loff[threadIdx.x - o] : 0u;
        __syncthreads();
        loff[threadIdx.x] += a;
        __syncthreads();
    }
    unsigned int ex = loff[threadIdx.x] - v;
    ncur[threadIdx.x] = ex;
    int node = node0 + threadIdx.x;
    if (node < N) {
        off[node] = base + ex;
        deg[node] = v;
        float di = 1.0f / sqrtf((float)(v + 1u));  // +1 self loop
        dinv[node] = di;
        ttx[node] = di * x[node];
    }
    __syncthreads();
    for (unsigned int t = threadIdx.x; t < m; t += 256) {
        unsigned int rec = staged[(size_t)base + t];
        unsigned int p = atomicAdd(&ncur[rec >> SRC_BITS], 1u);
        csr[(size_t)base + p] = rec & SRC_MASK;
    }
}

// ---------------- LUT build (65 blocks); block 0 also inits bcur ----------------
__global__ __launch_bounds__(256) void lut_kernel(const float* __restrict__ W1, const float* __restrict__ b1,
                                                  const float* __restrict__ W2,
                                                  float* __restrict__ Alut, float* __restrict__ Blut,
                                                  float* __restrict__ tvals,
                                                  unsigned int* __restrict__ bcur, int NB) {
    __shared__ float w1[64], bb[64], tv[64];
    __shared__ int rnk[64];
    __shared__ float sW2[64 * 32];
    __shared__ double red[2][256];
    int tid = threadIdx.x;
    if (blockIdx.x == 0) {
        for (int t = tid; t < NB; t += 256) bcur[t] = (unsigned int)t * BCAP;
    }
    if (tid < 64) {
        float w = W1[tid], b = b1[tid];
        w1[tid] = w; bb[tid] = b;
        tv[tid] = (w != 0.f) ? (-b / w) : __uint_as_float(0x7F800000u);  // +inf for degenerate
    }
    for (int t = tid; t < 64 * 32; t += 256) sW2[t] = W2[t];
    __syncthreads();
    if (tid < 64) {
        int r = 0;
        float tj = tv[tid];
        for (int k = 0; k < 64; ++k)
            if (w1[k] != 0.f && (tv[k] < tj || (tv[k] == tj && k < tid))) ++r;
        rnk[tid] = r;
        if (blockIdx.x == 0) tvals[tid] = tv[tid];
    }
    __syncthreads();
    int s = blockIdx.x;                 // segment 0..64
    int c = tid & 31, slice = tid >> 5; // 8 j-slices x 32 channels
    double da = 0.0, db = 0.0;
#pragma unroll
    for (int u = 0; u < 8; ++u) {
        int j = slice * 8 + u;
        float w = w1[j];
        bool act = (w > 0.f) ? (rnk[j] < s) : ((w < 0.f) ? (rnk[j] >= s) : (bb[j] > 0.f));
        if (act) {
            double w2 = (double)sW2[j * 32 + c];
            da += (double)w * w2;
            db += (double)bb[j] * w2;
        }
    }
    red[0][tid] = da; red[1][tid] = db;
    __syncthreads();
    for (int o = 128; o >= 32; o >>= 1) {
        if (tid < o) { red[0][tid] += red[0][tid + o]; red[1][tid] += red[1][tid + o]; }
        __syncthreads();
    }
    if (tid < 32) {
        Alut[s * 32 + tid] = (float)red[0][tid];
        Blut[s * 32 + tid] = (float)red[1][tid];
    }
}

// ---------------- layer-1 gather + fused segment classification -> recs ----------------
__global__ __launch_bounds__(256) void gather1_kernel(const unsigned int* __restrict__ csr,
                                                      const unsigned int* __restrict__ off,
                                                      const unsigned int* __restrict__ deg,
                                                      const float* __restrict__ dinv,
                                                      const float* __restrict__ tt,
                                                      const float* __restrict__ tvals,
                                                      uint4* __restrict__ recs, int N) {
    __shared__ float st[64];
    for (int t = threadIdx.x; t < 64; t += 256) st[t] = tvals[t];
    __syncthreads();
    int tid = blockIdx.x * 256 + threadIdx.x;
    int i = tid >> 2, l = tid & 3;
    if (i >= N) return;
    unsigned int o = off[i], n = deg[i];
    float acc0 = 0.f, acc1 = 0.f;
    unsigned int k = l;
    for (; k + 4 < n; k += 8) { acc0 += tt[csr[o + k]]; acc1 += tt[csr[o + k + 4]]; }
    if (k < n) acc0 += tt[csr[o + k]];
    float acc = acc0 + acc1;
    acc += __shfl_xor(acc, 1, 4);
    acc += __shfl_xor(acc, 2, 4);
    float di = dinv[i];
    float a = di * (acc + tt[i]);        // agg1 (all 4 lanes hold it)
    unsigned int cv = 0;
#pragma unroll
    for (int j = 0; j < 16; ++j) cv += (st[l * 16 + j] < a) ? 1u : 0u;
    cv += __shfl_xor(cv, 1, 4);
    cv += __shfl_xor(cv, 2, 4);
    if (l == 0) recs[i] = make_uint4(__float_as_uint(a * di), __float_as_uint(di), cv, 0u);
}

// ---------------- layer-2 LUT gather + in-register shuffle transform -> tt3 ----------------
// 8 lanes/node (lane owns channels cc, cc+8, cc+16, cc+24): 8 groups/wave;
// 2-stage rotating pipeline (csr pair j+2, recs pair j+1 in flight while FMA pair j).
#define G2_ITERS 4
#define FMA4(R, ACC)                                                          \
    {                                                                         \
        float4 A_ = sA2[(R).z * 8 + cc], B_ = sB2[(R).z * 8 + cc];            \
        float p_ = __uint_as_float((R).x), q_ = __uint_as_float((R).y);       \
        (ACC).x = fmaf(A_.x, p_, fmaf(B_.x, q_, (ACC).x));                    \
        (ACC).y = fmaf(A_.y, p_, fmaf(B_.y, q_, (ACC).y));                    \
        (ACC).z = fmaf(A_.z, p_, fmaf(B_.z, q_, (ACC).z));                    \
        (ACC).w = fmaf(A_.w, p_, fmaf(B_.w, q_, (ACC).w));                    \
    }
__global__ __launch_bounds__(256) void gather2t3_kernel(const unsigned int* __restrict__ csr,
                                                        const unsigned int* __restrict__ off,
                                                        const unsigned int* __restrict__ deg,
                                                        const float* __restrict__ dinv,
                                                        const uint4* __restrict__ recs,
                                                        const float* __restrict__ Alut, const float* __restrict__ Blut,
                                                        const float* __restrict__ b2, const float* __restrict__ W3,
                                                        float* __restrict__ tt3, int N) {
    __shared__ float4 sA2[65 * 8], sB2[65 * 8];
    __shared__ float2 sW3p[32 * 8];
    __shared__ float sb2[32];
    for (int t = threadIdx.x; t < 65 * 8; t += 256) {
        int s = t >> 3, q = t & 7;
        sA2[t] = make_float4(Alut[s * 32 + q], Alut[s * 32 + q + 8],
                             Alut[s * 32 + q + 16], Alut[s * 32 + q + 24]);
        sB2[t] = make_float4(Blut[s * 32 + q], Blut[s * 32 + q + 8],
                             Blut[s * 32 + q + 16], Blut[s * 32 + q + 24]);
    }
    for (int t = threadIdx.x; t < 32 * 8; t += 256) {
        int k = t >> 3, q = t & 7;
        sW3p[t] = make_float2(W3[k * 16 + q], W3[k * 16 + q + 8]);
    }
    if (threadIdx.x < 32) sb2[threadIdx.x] = b2[threadIdx.x];
    __syncthreads();

    int g = threadIdx.x >> 3, cc = threadIdx.x & 7;
    for (int iter = 0; iter < G2_ITERS; ++iter) {
        int d = blockIdx.x * (32 * G2_ITERS) + iter * 32 + g;
        if (d >= N) continue;                 // uniform within the 8-lane group
        float dd = dinv[d];
        unsigned int o = off[d], n = deg[d];
        uint4 rs = recs[d];
        float ps = __uint_as_float(rs.x), qs = __uint_as_float(rs.y);
        float4 As = sA2[rs.z * 8 + cc], Bs = sB2[rs.z * 8 + cc];
        float4 aP, aQ;
        aP.x = fmaf(As.x, ps, Bs.x * qs); aP.y = fmaf(As.y, ps, Bs.y * qs);
        aP.z = fmaf(As.z, ps, Bs.z * qs); aP.w = fmaf(As.w, ps, Bs.w * qs);
        aQ = make_float4(0.f, 0.f, 0.f, 0.f);
        unsigned int P = n >> 1;
        if (P >= 2) {
            unsigned int c0 = csr[o], c1 = csr[o + 1];
            unsigned int c2 = csr[o + 2], c3 = csr[o + 3];
            uint4 r0 = recs[c0], r1 = recs[c1];
            for (unsigned int j = 0; j + 2 < P; ++j) {
                unsigned int base = o + 2 * j;
                unsigned int nc0 = csr[base + 4], nc1 = csr[base + 5];  // csr pair j+2
                uint4 nr0 = recs[c2], nr1 = recs[c3];                   // recs pair j+1
                FMA4(r0, aP); FMA4(r1, aQ);                             // FMA pair j
                r0 = nr0; r1 = nr1; c2 = nc0; c3 = nc1;
            }
            uint4 m0 = recs[c2], m1 = recs[c3];
            FMA4(r0, aP); FMA4(r1, aQ);
            FMA4(m0, aP); FMA4(m1, aQ);
        } else if (P == 1) {
            uint4 r0 = recs[csr[o]], r1 = recs[csr[o + 1]];
            FMA4(r0, aP); FMA4(r1, aQ);
        }
        if (n & 1u) {
            uint4 r0 = recs[csr[o + n - 1]];
            FMA4(r0, aP);
        }
        float hv0 = fmaxf(fmaf(dd, aP.x + aQ.x, sb2[cc]), 0.f);
        float hv1 = fmaxf(fmaf(dd, aP.y + aQ.y, sb2[cc + 8]), 0.f);
        float hv2 = fmaxf(fmaf(dd, aP.z + aQ.z, sb2[cc + 16]), 0.f);
        float hv3 = fmaxf(fmaf(dd, aP.w + aQ.w, sb2[cc + 24]), 0.f);

        // in-register W3 transform: t3[c] = sum_k h2[k]*W3[k][c], c in {cc, cc+8}
        float t0 = 0.f, t1 = 0.f;
#pragma unroll
        for (int l2 = 0; l2 < 8; ++l2) {
            float hk = __shfl(hv0, l2, 8);
            float2 w = sW3p[l2 * 8 + cc];
            t0 = fmaf(hk, w.x, t0); t1 = fmaf(hk, w.y, t1);
        }
#pragma unroll
        for (int l2 = 0; l2 < 8; ++l2) {
            float hk = __shfl(hv1, l2, 8);
            float2 w = sW3p[(8 + l2) * 8 + cc];
            t0 = fmaf(hk, w.x, t0); t1 = fmaf(hk, w.y, t1);
        }
#pragma unroll
        for (int l2 = 0; l2 < 8; ++l2) {
            float hk = __shfl(hv2, l2, 8);
            float2 w = sW3p[(16 + l2) * 8 + cc];
            t0 = fmaf(hk, w.x, t0); t1 = fmaf(hk, w.y, t1);
        }
#pragma unroll
        for (int l2 = 0; l2 < 8; ++l2) {
            float hk = __shfl(hv3, l2, 8);
            float2 w = sW3p[(24 + l2) * 8 + cc];
            t0 = fmaf(hk, w.x, t0); t1 = fmaf(hk, w.y, t1);
        }
        tt3[(size_t)d * 16 + cc] = dd * t0;
        tt3[(size_t)d * 16 + cc + 8] = dd * t1;
    }
}

// ---------------- layer-3 gather (float4, 4 lanes/node, csr 1-quad ahead) -> tt4 ----------------
__global__ __launch_bounds__(256) void gather3t4_kernel(const unsigned int* __restrict__ csr,
                                                        const unsigned int* __restrict__ off,
                                                        const unsigned int* __restrict__ deg,
                                                        const float* __restrict__ dinv,
                                                        const float* __restrict__ tt3,
                                                        const float* __restrict__ b3, const float* __restrict__ W4,
                                                        float* __restrict__ tt4, int N) {
    int tid = blockIdx.x * 256 + threadIdx.x;
    int d = tid >> 2, l = tid & 3;
    if (d >= N) return;
    float dd = dinv[d];
    unsigned int o = off[d], n = deg[d];
    const float4* t34 = reinterpret_cast<const float4*>(tt3);
    float4 acc = t34[(size_t)d * 4 + l];   // self term
    float4 acc1 = make_float4(0.f, 0.f, 0.f, 0.f);
    unsigned int k = 0;
    if (n >= 4) {
        unsigned int s0 = csr[o], s1 = csr[o + 1], s2 = csr[o + 2], s3 = csr[o + 3];
        k = 4;
        for (; k + 3 < n; k += 4) {
            unsigned int t0 = csr[o + k], t1 = csr[o + k + 1], t2 = csr[o + k + 2], t3 = csr[o + k + 3];
            float4 v0 = t34[(size_t)s0 * 4 + l];
            float4 v1 = t34[(size_t)s1 * 4 + l];
            float4 v2 = t34[(size_t)s2 * 4 + l];
            float4 v3 = t34[(size_t)s3 * 4 + l];
            acc.x += v0.x + v2.x; acc.y += v0.y + v2.y; acc.z += v0.z + v2.z; acc.w += v0.w + v2.w;
            acc1.x += v1.x + v3.x; acc1.y += v1.y + v3.y; acc1.z += v1.z + v3.z; acc1.w += v1.w + v3.w;
            s0 = t0; s1 = t1; s2 = t2; s3 = t3;
        }
        {   // drain in-flight quad
            float4 v0 = t34[(size_t)s0 * 4 + l];
            float4 v1 = t34[(size_t)s1 * 4 + l];
            float4 v2 = t34[(size_t)s2 * 4 + l];
            float4 v3 = t34[(size_t)s3 * 4 + l];
            acc.x += v0.x + v2.x; acc.y += v0.y + v2.y; acc.z += v0.z + v2.z; acc.w += v0.w + v2.w;
            acc1.x += v1.x + v3.x; acc1.y += v1.y + v3.y; acc1.z += v1.z + v3.z; acc1.w += v1.w + v3.w;
        }
    }
    for (; k < n; ++k) {
        float4 v0 = t34[(size_t)csr[o + k] * 4 + l];
        acc.x += v0.x; acc.y += v0.y; acc.z += v0.z; acc.w += v0.w;
    }
    acc.x += acc1.x; acc.y += acc1.y; acc.z += acc1.z; acc.w += acc1.w;
    float4 b3v = reinterpret_cast<const float4*>(b3)[l];
    float4 w4v = reinterpret_cast<const float4*>(W4)[l];
    float v = fmaxf(fmaf(dd, acc.x, b3v.x), 0.f) * w4v.x;
    v = fmaf(fmaxf(fmaf(dd, acc.y, b3v.y), 0.f), w4v.y, v);
    v = fmaf(fmaxf(fmaf(dd, acc.z, b3v.z), 0.f), w4v.z, v);
    v = fmaf(fmaxf(fmaf(dd, acc.w, b3v.w), 0.f), w4v.w, v);
    v += __shfl_xor(v, 1, 4);
    v += __shfl_xor(v, 2, 4);
    if (l == 0) tt4[d] = dd * v;
}

// ---------------- layer-4 scalar gather -> out ----------------
__global__ void gather4_kernel(const unsigned int* __restrict__ csr, const unsigned int* __restrict__ off,
                               const unsigned int* __restrict__ deg, const float* __restrict__ dinv,
                               const float* __restrict__ tt, const float* __restrict__ b4,
                               float* __restrict__ out, int N) {
    int tid = blockIdx.x * blockDim.x + threadIdx.x;
    int i = tid >> 2, l = tid & 3;
    if (i >= N) return;
    unsigned int o = off[i], n = deg[i];
    float acc0 = 0.f, acc1 = 0.f;
    unsigned int k = l;
    for (; k + 4 < n; k += 8) { acc0 += tt[csr[o + k]]; acc1 += tt[csr[o + k + 4]]; }
    if (k < n) acc0 += tt[csr[o + k]];
    float acc = acc0 + acc1;
    acc += __shfl_xor(acc, 1, 4);
    acc += __shfl_xor(acc, 2, 4);
    if (l == 0) out[i] = dinv[i] * (acc + tt[i]) + b4[0];
}

extern "C" void kernel_launch(void* const* d_in, const int* in_sizes, int n_in,
                              void* d_out, int out_size, void* d_ws, size_t ws_size,
                              hipStream_t stream) {
    const float* x  = (const float*)d_in[0];
    const int* eidx = (const int*)d_in[1];
    const float* W1 = (const float*)d_in[2];
    const float* b1 = (const float*)d_in[3];
    const float* W2 = (const float*)d_in[4];
    const float* b2 = (const float*)d_in[5];
    const float* W3 = (const float*)d_in[6];
    const float* b3 = (const float*)d_in[7];
    const float* W4 = (const float*)d_in[8];
    const float* b4 = (const float*)d_in[9];
    float* out = (float*)d_out;

    const int N = in_sizes[0];         // 100000
    const int E = in_sizes[1] / 2;     // 3200000
    const int* src = eidx;
    const int* dst = eidx + E;
    const int NB = (N + NPB - 1) >> NPB_SHIFT;   // 391 buckets

    char* ws = (char*)d_ws;
    unsigned int* bcur  = (unsigned int*)ws;  ws += MAXB * 4;
    float* tvals = (float*)ws;                ws += 64 * 4;
    float* Alut  = (float*)ws;                ws += 65 * 32 * 4;
    float* Blut  = (float*)ws;                ws += 65 * 32 * 4;
    unsigned int* off = (unsigned int*)ws;    ws += (size_t)N * 4;
    unsigned int* deg = (unsigned int*)ws;    ws += (size_t)N * 4;
    float* dinv = (float*)ws;                 ws += (size_t)N * 4;
    float* ttx  = (float*)ws;                 ws += (size_t)N * 4;
    float* tt4  = (float*)ws;                 ws += (size_t)N * 4;
    uint4* recs = (uint4*)ws;                 ws += (size_t)N * 16;
    unsigned int* csr = (unsigned int*)ws;    ws += (size_t)NB * BCAP * 4;   // padded CSR (14.4MB)
    unsigned int* staged = (unsigned int*)ws; // padded staged; tt3 (6.4MB) aliases it
    float* tt3 = (float*)staged;              // staged dead after build_csr

    const int nPartBlocks = (E + EPB - 1) / EPB;   // 782

    lut_kernel<<<65, 256, 0, stream>>>(W1, b1, W2, Alut, Blut, tvals, bcur, NB);
    partition_kernel<<<nPartBlocks, 256, 0, stream>>>(src, dst, bcur, staged, E, NB);
    build_csr_kernel<<<NB, 256, 0, stream>>>(staged, bcur, x, csr, off, deg, dinv, ttx, N);

    gather1_kernel<<<((size_t)N * 4 + 255) / 256, 256, 0, stream>>>(csr, off, deg, dinv, ttx, tvals, recs, N);
    gather2t3_kernel<<<(N + 32 * G2_ITERS - 1) / (32 * G2_ITERS), 256, 0, stream>>>(csr, off, deg, dinv, recs, Alut, Blut, b2, W3, tt3, N);
    gather3t4_kernel<<<((size_t)N * 4 + 255) / 256, 256, 0, stream>>>(csr, off, deg, dinv, tt3, b3, W4, tt4, N);
    gather4_kernel<<<((size_t)N * 4 + 255) / 256, 256, 0, stream>>>(csr, off, deg, dinv, tt4, b4, out, N);
}